// Round 14
// baseline (130.220 us; speedup 1.0000x reference)
//
#include <hip/hip_runtime.h>
#include <hip/hip_bf16.h>

typedef unsigned short u16;
typedef unsigned int u32;
typedef __attribute__((ext_vector_type(8))) short bf16x8;   // 8 bf16 (MFMA x32 A/B frag)
typedef __attribute__((ext_vector_type(4))) float f32x4;    // MFMA C/D frag

#define BB 4
#define NN 2048
#define DD 256
#define HH 8
#define LAMBDA (-0.2550351f)  // -log2(e)/sqrt(32): folded into Q so sigmoid = rcp(1+exp2(s))

__device__ inline u16 bfu(float f) {
  __hip_bfloat16 h = __float2bfloat16(f);
  return *reinterpret_cast<u16*>(&h);
}
__device__ inline bf16x8 asfrag(uint4 v) { return __builtin_bit_cast(bf16x8, v); }

// ---------------- merged prep: x(permuted)+xb, mask->u8, weights ----------------
__global__ __launch_bounds__(256) void prep_kernel(
    const float* __restrict__ qdt, const float* __restrict__ boxes,
    const int* __restrict__ mask,
    const float* __restrict__ Wq, const float* __restrict__ Wk, const float* __restrict__ Wv,
    const float* __restrict__ Wo, const float* __restrict__ W1, const float* __restrict__ W2,
    const float* __restrict__ bq, const float* __restrict__ bk, const float* __restrict__ bv,
    float* __restrict__ xp, u16* __restrict__ xb, unsigned char* __restrict__ m8,
    u16* __restrict__ wqkvT, u16* __restrict__ woT, u16* __restrict__ w1T, u16* __restrict__ w2T,
    float* __restrict__ bqkv) {
  const int bid = blockIdx.x, t = threadIdx.x;
  if (bid < 2048) {                       // x = qdt + boxes (permuted fp32 + linear bf16)
    int i = bid * 256 + t;
    int row = i >> 6, q = i & 63;
    float4 a = ((const float4*)qdt)[i];
    float4 b = ((const float4*)boxes)[i];
    float4 v = make_float4(a.x + b.x, a.y + b.y, a.z + b.z, a.w + b.w);
    ((ushort4*)xb)[i] = make_ushort4(bfu(v.x), bfu(v.y), bfu(v.z), bfu(v.w));
    float* xr = xp + (size_t)row * 256;
    xr[((4*q+0) & 15) * 16 + ((4*q+0) >> 4)] = v.x;
    xr[((4*q+1) & 15) * 16 + ((4*q+1) >> 4)] = v.y;
    xr[((4*q+2) & 15) * 16 + ((4*q+2) >> 4)] = v.z;
    xr[((4*q+3) & 15) * 16 + ((4*q+3) >> 4)] = v.w;
  } else if (bid < 6144) {                // mask int -> u8 0/1
    int i = (bid - 2048) * 256 + t;
    int4 m = ((const int4*)mask)[i];
    ((uchar4*)m8)[i] = make_uchar4((unsigned char)m.x, (unsigned char)m.y,
                                   (unsigned char)m.z, (unsigned char)m.w);
  } else {                                // weight transposes + qkv bias concat
    int i = (bid - 6144) * 256 + t;
    if (i < 196608) {
      int n = i >> 8, k = i & 255;
      const float* src = (n < 256) ? Wq : (n < 512 ? Wk : Wv);
      wqkvT[i] = bfu(src[k * 256 + (n & 255)]);
    } else if (i < 262144) {
      int j = i - 196608; int n = j >> 8, k = j & 255;
      woT[j] = bfu(Wo[k * 256 + n]);
    } else if (i < 327680) {
      int j = i - 262144; int n = j >> 8, k = j & 255;
      w1T[j] = bfu(W1[k * 256 + n]);
    } else if (i < 393216) {
      int j = i - 327680; int n = j >> 8, k = j & 255;
      w2T[j] = bfu(W2[k * 256 + n]);
    } else if (i < 393984) {
      int n = i - 393216;
      bqkv[n] = (n < 256) ? bq[n] : (n < 512 ? bk[n - 256] : bv[n - 512]);
    }
  }
}

// ---------------- fused QKV-side GEMM: Q(scaled)+K(relayout) and V^T in one launch -------
__global__ __launch_bounds__(256) void gemm_qkvt_kernel(
    const u16* __restrict__ xb, const u16* __restrict__ wqkvT,
    const float* __restrict__ bqkv,
    u16* __restrict__ qout, u16* __restrict__ kout, u16* __restrict__ vtout) {
  __shared__ u16 At[64][264];
  __shared__ u16 Bs[64][264];
  const int bid = blockIdx.x;
  const bool isqk = bid < 1024;
  const u16* A  = isqk ? xb : (wqkvT + 512 * 256);
  const u16* Bt = isqk ? wqkvT : xb;
  const int m0 = isqk ? (bid >> 3) * 64 : ((bid - 1024) >> 7) * 64;
  const int n0 = isqk ? (bid & 7) * 64 : ((bid - 1024) & 127) * 64;
  const int t = threadIdx.x;
  {
    const int row = t >> 2, cb = (t & 3) * 64;
    const u16* ga = A  + (size_t)(m0 + row) * 256 + cb;
    const u16* gb = Bt + (size_t)(n0 + row) * 256 + cb;
#pragma unroll
    for (int i = 0; i < 8; ++i) {
      *(int4*)&At[row][cb + i * 8] = *(const int4*)(ga + i * 8);
      *(int4*)&Bs[row][cb + i * 8] = *(const int4*)(gb + i * 8);
    }
  }
  __syncthreads();
  const int w = t >> 6, l = t & 63, g = l >> 4, c = l & 15;
  f32x4 acc[4] = {};
#pragma unroll
  for (int kk = 0; kk < 256; kk += 32) {
    bf16x8 af = *(const bf16x8*)&At[w * 16 + c][kk + g * 8];
#pragma unroll
    for (int j = 0; j < 4; ++j) {
      bf16x8 bfr = *(const bf16x8*)&Bs[j * 16 + c][kk + g * 8];
      acc[j] = __builtin_amdgcn_mfma_f32_16x16x32_bf16(af, bfr, acc[j], 0, 0, 0);
    }
  }
  if (isqk) {
    if (n0 < 256) {
#pragma unroll
      for (int j = 0; j < 4; ++j)
#pragma unroll
        for (int r = 0; r < 4; ++r) {
          int m = m0 + w * 16 + g * 4 + r, n = n0 + j * 16 + c;
          qout[(size_t)m * 256 + n] = bfu((acc[j][r] + bqkv[n]) * LAMBDA);
        }
    } else {
#pragma unroll
      for (int j = 0; j < 4; ++j)
#pragma unroll
        for (int r = 0; r < 4; ++r) {
          int m = m0 + w * 16 + g * 4 + r, n = n0 + j * 16 + c;
          int ch = n - 256;
          kout[(size_t)((m >> 11) * 8 + (ch >> 5)) * 65536 + (size_t)(m & 2047) * 32 + (ch & 31)]
              = bfu(acc[j][r] + bqkv[n]);
        }
    }
  } else {
#pragma unroll
    for (int j = 0; j < 4; ++j)
#pragma unroll
      for (int r = 0; r < 4; ++r) {
        int m = m0 + w * 16 + g * 4 + r;   // channel
        int n = n0 + j * 16 + c;           // token
        vtout[(size_t)m * 8192 + n] = bfu(acc[j][r] + bqkv[512 + m]);
      }
  }
}

// ---------------- fused sigmoid-gated attention ----------------
// = round-12 PASSING build with ONE change: mask u32 loaded DIRECTLY from
//   global (L2/L3-resident m8) inside the tt loop -- Mlds staging deleted.
//   Staging saved zero traffic (mask is read-once per (b,h,q-tile)); removing
//   it cuts ~40cy/iter of LDS issue + rotation math and drops LDS
//   36.9->28.7 KB (4 -> 5 blocks/CU).
//   NOT the quarantined r2-r5 pattern: u8 format, in-iteration load,
//   float-mul gate -- each proven green individually.
__global__ __launch_bounds__(256) void attn_kernel(
    const u16* __restrict__ qb,            // [8192][256] bf16, LAMBDA-scaled
    const u16* __restrict__ kb,            // [B][H][2048][32] bf16
    const u16* __restrict__ vtb,           // [256][8192] bf16 (V^T)
    const unsigned char* __restrict__ m8,  // [2048][2048] 0/1
    u16* __restrict__ ob) {                // [8192][256] bf16
  __shared__ u32 Klds[2][64][20];          // 16 data u32 + 4 pad (row 80 B)
  __shared__ u32 Vlds[2][32][36];          // 32 data u32 + 4 pad (row 144 B)
  __shared__ u32 Plds[4][16][36];          // 32 data u32 + 4 pad, per-wave

  const int bid = blockIdx.x;
  const int qt = bid & 31, h = (bid >> 5) & 7, b = bid >> 8;
  const int q0 = qt * 64;
  const int t = threadIdx.x, w = t >> 6, l = t & 63, g = l >> 4, c = l & 15;

  const bf16x8 qf = asfrag(*(const uint4*)(qb + (size_t)(b * NN + q0 + 16 * w + c) * 256 + h * 32 + 8 * g));
  f32x4 oacc[2] = {};

  const int srowK = t >> 2, ssegK = t & 3;
  const int srowV = t >> 3, ssegV = t & 7;
  const u16* kg = kb + (size_t)(b * 8 + h) * 65536 + srowK * 32 + ssegK * 8;
  const u16* vg = vtb + (size_t)(h * 32 + srowV) * 8192 + (size_t)b * NN + ssegV * 8;
  const unsigned char* mrow = m8 + (size_t)(q0 + 16 * w + c) * 2048 + 4 * g;  // lane's q-row

  uint4 krg = *(const uint4*)kg;
  uint4 vrg = *(const uint4*)vg;
  *(uint4*)&Klds[0][srowK][ssegK * 4] = krg;
  *(uint4*)&Vlds[0][srowV][ssegV * 4] = vrg;
  __syncthreads();

  const f32x4 zf = {0.f, 0.f, 0.f, 0.f};
  u32* Pw = &Plds[w][0][0];

  for (int it = 0; it < 32; ++it) {
    const int cur = it & 1;
    const int kt = it * 64;
    if (it < 31) {
      krg = *(const uint4*)(kg + (size_t)(kt + 64) * 32);
      vrg = *(const uint4*)(vg + kt + 64);
    }
#pragma unroll
    for (int tt = 0; tt < 4; ++tt) {
      bf16x8 kf = asfrag(*(const uint4*)&Klds[cur][16 * tt + c][4 * g]);
      f32x4 s = __builtin_amdgcn_mfma_f32_16x16x32_bf16(kf, qf, zf, 0, 0, 0);
      u32 mdw = *(const u32*)(mrow + kt + 16 * tt);   // 4 mask bytes: k = kt+16tt+4g..+3
      float mf0 = (float)(mdw & 0xffu);
      float mf1 = (float)((mdw >> 8) & 0xffu);
      float mf2 = (float)((mdw >> 16) & 0xffu);
      float mf3 = (float)(mdw >> 24);
      float p0 = mf0 * __builtin_amdgcn_rcpf(1.f + __builtin_amdgcn_exp2f(s[0]));
      float p1 = mf1 * __builtin_amdgcn_rcpf(1.f + __builtin_amdgcn_exp2f(s[1]));
      float p2 = mf2 * __builtin_amdgcn_rcpf(1.f + __builtin_amdgcn_exp2f(s[2]));
      float p3 = mf3 * __builtin_amdgcn_rcpf(1.f + __builtin_amdgcn_exp2f(s[3]));
      u32 w0, w1;
      asm("v_cvt_pk_bf16_f32 %0, %1, %2" : "=v"(w0) : "v"(p0), "v"(p1));
      asm("v_cvt_pk_bf16_f32 %0, %1, %2" : "=v"(w1) : "v"(p2), "v"(p3));
      *(uint2*)&Pw[c * 36 + 8 * tt + 2 * g] = make_uint2(w0, w1);
    }
    asm volatile("s_waitcnt lgkmcnt(0)" ::: "memory");
    __builtin_amdgcn_sched_barrier(0);
#pragma unroll
    for (int kk = 0; kk < 2; ++kk) {
      bf16x8 pf = asfrag(*(const uint4*)&Pw[c * 36 + 16 * kk + 4 * g]);
#pragma unroll
      for (int d0 = 0; d0 < 2; ++d0) {
        bf16x8 vf = asfrag(*(const uint4*)&Vlds[cur][16 * d0 + c][16 * kk + 4 * g]);
        oacc[d0] = __builtin_amdgcn_mfma_f32_16x16x32_bf16(pf, vf, oacc[d0], 0, 0, 0);
      }
    }
    if (it < 31) {
      *(uint4*)&Klds[cur ^ 1][srowK][ssegK * 4] = krg;
      *(uint4*)&Vlds[cur ^ 1][srowV][ssegV * 4] = vrg;
    }
    __syncthreads();
  }

  const size_t obase = (size_t)(b * NN + q0 + 16 * w) * 256 + h * 32;
#pragma unroll
  for (int d0 = 0; d0 < 2; ++d0)
#pragma unroll
    for (int r = 0; r < 4; ++r)
      ob[obase + (size_t)(4 * g + r) * 256 + 16 * d0 + c] = bfu(oacc[d0][r]);
}

// ---------------- fused tail v3: Wo+res -> LN1 -> FF1+relu -> FF2+res -> LN2 -------------
// (unchanged from round-12 PASSING build)
__global__ __launch_bounds__(256) void tail_kernel(
    const u16* __restrict__ obuf, const u16* __restrict__ woT,
    const u16* __restrict__ w1T, const u16* __restrict__ w2T,
    const float* __restrict__ xp,          // [8192][256] f32, permuted [row][c*16+4w+j]
    const float* __restrict__ bo, const float* __restrict__ b1, const float* __restrict__ b2,
    const float* __restrict__ g1, const float* __restrict__ be1,
    const float* __restrict__ g2, const float* __restrict__ be2,
    float* __restrict__ out) {
  __shared__ u16 A[32][264];               // bf16 activation tile
  __shared__ float PS1[32][4], PS2[32][4]; // cross-wave LN partials
  const int t = threadIdx.x, w = t >> 6, l = t & 63, g = l >> 4, c = l & 15;
  const int m0 = blockIdx.x * 32;          // block's 32 rows
  const int n0 = w * 64;                   // wave's 64 cols
  const f32x4 zf4 = {0.f, 0.f, 0.f, 0.f};

  // ---- stage obuf rows m0..m0+31 (256 threads, 4 x 16B each) ----
  {
    const int srow = t >> 3, sseg = t & 7;
#pragma unroll
    for (int i = 0; i < 4; ++i) {
      uint4 v = *(const uint4*)(obuf + (size_t)(m0 + srow) * 256 + (sseg + 8 * i) * 8);
      *(uint4*)&A[srow][(sseg + 8 * i) * 8] = v;
    }
  }
  __syncthreads();

  f32x4 acc[2][4], t1[2][4];
  float mean[2][4], inv[2][4];

  // ---- GEMM1: obuf @ Wo ----
#pragma unroll
  for (int rg = 0; rg < 2; ++rg)
#pragma unroll
    for (int j = 0; j < 4; ++j) acc[rg][j] = zf4;
#pragma unroll
  for (int kk = 0; kk < 256; kk += 32) {
    bf16x8 af0 = *(const bf16x8*)&A[c][kk + 8 * g];
    bf16x8 af1 = *(const bf16x8*)&A[16 + c][kk + 8 * g];
#pragma unroll
    for (int j = 0; j < 4; ++j) {
      bf16x8 bfr = asfrag(*(const uint4*)(woT + (size_t)(n0 + 16 * j + c) * 256 + kk + 8 * g));
      acc[0][j] = __builtin_amdgcn_mfma_f32_16x16x32_bf16(af0, bfr, acc[0][j], 0, 0, 0);
      acc[1][j] = __builtin_amdgcn_mfma_f32_16x16x32_bf16(af1, bfr, acc[1][j], 0, 0, 0);
    }
  }
  // ---- epilogue1: z = acc + bo + x -> t1 regs; LN1 partials -> PS ----
  {
    float bov[4];
#pragma unroll
    for (int j = 0; j < 4; ++j) bov[j] = bo[n0 + 16 * j + c];
#pragma unroll
    for (int rg = 0; rg < 2; ++rg)
#pragma unroll
      for (int r = 0; r < 4; ++r) {
        const int rl = 16 * rg + 4 * g + r;
        float4 xq = ((const float4*)(xp + (size_t)(m0 + rl) * 256 + c * 16))[w];
        float xa[4] = {xq.x, xq.y, xq.z, xq.w};
        float a1 = 0.f, a2 = 0.f;
#pragma unroll
        for (int j = 0; j < 4; ++j) {
          float z = acc[rg][j][r] + bov[j] + xa[j];
          t1[rg][j][r] = z;
          a1 += z; a2 += z * z;
        }
#pragma unroll
        for (int off = 1; off < 16; off <<= 1) {
          a1 += __shfl_xor(a1, off);
          a2 += __shfl_xor(a2, off);
        }
        if (c == 0) { PS1[rl][w] = a1; PS2[rl][w] = a2; }
      }
  }
  __syncthreads();
#pragma unroll
  for (int rg = 0; rg < 2; ++rg)
#pragma unroll
    for (int r = 0; r < 4; ++r) {
      const int rl = 16 * rg + 4 * g + r;
      float s1 = PS1[rl][0] + PS1[rl][1] + PS1[rl][2] + PS1[rl][3];
      float s2 = PS2[rl][0] + PS2[rl][1] + PS2[rl][2] + PS2[rl][3];
      mean[rg][r] = s1 * (1.f / 256.f);
      inv[rg][r] = rsqrtf(s2 * (1.f / 256.f) - mean[rg][r] * mean[rg][r] + 1e-5f);
    }
  // normalize into t1 regs (kept for FF2 residual) + bf16 tile -> A
#pragma unroll
  for (int j = 0; j < 4; ++j) {
    const int n = n0 + 16 * j + c;
    const float gv = g1[n], bev = be1[n];
#pragma unroll
    for (int rg = 0; rg < 2; ++rg)
#pragma unroll
      for (int r = 0; r < 4; ++r) {
        float v = (t1[rg][j][r] - mean[rg][r]) * inv[rg][r] * gv + bev;
        t1[rg][j][r] = v;
        A[16 * rg + 4 * g + r][n] = bfu(v);
      }
  }
  __syncthreads();

  // ---- GEMM2: t1 @ W1, relu ----
#pragma unroll
  for (int rg = 0; rg < 2; ++rg)
#pragma unroll
    for (int j = 0; j < 4; ++j) acc[rg][j] = zf4;
#pragma unroll
  for (int kk = 0; kk < 256; kk += 32) {
    bf16x8 af0 = *(const bf16x8*)&A[c][kk + 8 * g];
    bf16x8 af1 = *(const bf16x8*)&A[16 + c][kk + 8 * g];
#pragma unroll
    for (int j = 0; j < 4; ++j) {
      bf16x8 bfr = asfrag(*(const uint4*)(w1T + (size_t)(n0 + 16 * j + c) * 256 + kk + 8 * g));
      acc[0][j] = __builtin_amdgcn_mfma_f32_16x16x32_bf16(af0, bfr, acc[0][j], 0, 0, 0);
      acc[1][j] = __builtin_amdgcn_mfma_f32_16x16x32_bf16(af1, bfr, acc[1][j], 0, 0, 0);
    }
  }
  __syncthreads();                         // all waves done reading A
#pragma unroll
  for (int j = 0; j < 4; ++j) {
    const int n = n0 + 16 * j + c;
    const float bv = b1[n];
#pragma unroll
    for (int rg = 0; rg < 2; ++rg)
#pragma unroll
      for (int r = 0; r < 4; ++r) {
        float v = acc[rg][j][r] + bv;
        A[16 * rg + 4 * g + r][n] = bfu(v > 0.f ? v : 0.f);
      }
  }
  __syncthreads();

  // ---- GEMM3: h @ W2 ----
#pragma unroll
  for (int rg = 0; rg < 2; ++rg)
#pragma unroll
    for (int j = 0; j < 4; ++j) acc[rg][j] = zf4;
#pragma unroll
  for (int kk = 0; kk < 256; kk += 32) {
    bf16x8 af0 = *(const bf16x8*)&A[c][kk + 8 * g];
    bf16x8 af1 = *(const bf16x8*)&A[16 + c][kk + 8 * g];
#pragma unroll
    for (int j = 0; j < 4; ++j) {
      bf16x8 bfr = asfrag(*(const uint4*)(w2T + (size_t)(n0 + 16 * j + c) * 256 + kk + 8 * g));
      acc[0][j] = __builtin_amdgcn_mfma_f32_16x16x32_bf16(af0, bfr, acc[0][j], 0, 0, 0);
      acc[1][j] = __builtin_amdgcn_mfma_f32_16x16x32_bf16(af1, bfr, acc[1][j], 0, 0, 0);
    }
  }
  // ---- epilogue3: z = acc + b2 + t1 (regs); LN2 -> out ----
  {
    float b2v[4];
#pragma unroll
    for (int j = 0; j < 4; ++j) b2v[j] = b2[n0 + 16 * j + c];
#pragma unroll
    for (int rg = 0; rg < 2; ++rg)
#pragma unroll
      for (int r = 0; r < 4; ++r) {
        const int rl = 16 * rg + 4 * g + r;
        float a1 = 0.f, a2 = 0.f;
#pragma unroll
        for (int j = 0; j < 4; ++j) {
          float z = acc[rg][j][r] + b2v[j] + t1[rg][j][r];
          t1[rg][j][r] = z;
          a1 += z; a2 += z * z;
        }
#pragma unroll
        for (int off = 1; off < 16; off <<= 1) {
          a1 += __shfl_xor(a1, off);
          a2 += __shfl_xor(a2, off);
        }
        if (c == 0) { PS1[rl][w] = a1; PS2[rl][w] = a2; }
      }
  }
  __syncthreads();
#pragma unroll
  for (int rg = 0; rg < 2; ++rg)
#pragma unroll
    for (int r = 0; r < 4; ++r) {
      const int rl = 16 * rg + 4 * g + r;
      float s1 = PS1[rl][0] + PS1[rl][1] + PS1[rl][2] + PS1[rl][3];
      float s2 = PS2[rl][0] + PS2[rl][1] + PS2[rl][2] + PS2[rl][3];
      mean[rg][r] = s1 * (1.f / 256.f);
      inv[rg][r] = rsqrtf(s2 * (1.f / 256.f) - mean[rg][r] * mean[rg][r] + 1e-5f);
    }
#pragma unroll
  for (int j = 0; j < 4; ++j) {
    const int n = n0 + 16 * j + c;
    const float gv = g2[n], bev = be2[n];
#pragma unroll
    for (int rg = 0; rg < 2; ++rg)
#pragma unroll
      for (int r = 0; r < 4; ++r)
        out[(size_t)(m0 + 16 * rg + 4 * g + r) * 256 + n]
            = (t1[rg][j][r] - mean[rg][r]) * inv[rg][r] * gv + bev;
  }
}

extern "C" void kernel_launch(void* const* d_in, const int* in_sizes, int n_in,
                              void* d_out, int out_size, void* d_ws, size_t ws_size,
                              hipStream_t stream) {
  const float* qdt   = (const float*)d_in[0];
  const float* boxes = (const float*)d_in[1];
  const int*   mask  = (const int*)d_in[2];
  const float* Wq = (const float*)d_in[3];
  const float* bq = (const float*)d_in[4];
  const float* Wk = (const float*)d_in[5];
  const float* bk = (const float*)d_in[6];
  const float* Wv = (const float*)d_in[7];
  const float* bv = (const float*)d_in[8];
  const float* Wo = (const float*)d_in[9];
  const float* bo = (const float*)d_in[10];
  const float* W1 = (const float*)d_in[11];
  const float* b1 = (const float*)d_in[12];
  const float* W2 = (const float*)d_in[13];
  const float* b2 = (const float*)d_in[14];
  const float* g1  = (const float*)d_in[15];
  const float* be1 = (const float*)d_in[16];
  const float* g2  = (const float*)d_in[17];
  const float* be2 = (const float*)d_in[18];

  char* ws = (char*)d_ws;
  float* xp    = (float*)(ws + 0);          // [8192,256] f32 permuted residual
  u16*   xb    = (u16*)  (ws + 8388608);
  u16*   qbuf  = (u16*)  (ws + 12582912);   // q, LAMBDA-scaled
  u16*   kbuf  = (u16*)  (ws + 16777216);   // [B][H][2048][32]
  u16*   vtbuf = (u16*)  (ws + 20971520);   // [256][8192]
  u16*   obuf  = (u16*)  (ws + 25165824);
  u16*   wqkvT = (u16*)  (ws + 46137344);   // [768,256]
  u16*   woT   = (u16*)  (ws + 46530560);
  u16*   w1T   = (u16*)  (ws + 46661632);
  u16*   w2T   = (u16*)  (ws + 46792704);
  float* bqkv  = (float*)(ws + 46923776);
  unsigned char* m8 = (unsigned char*)(ws + 46926848);  // [2048,2048] u8

  // merged prep: xp/xb (2048 blk) + mask->m8 (4096 blk) + weights (1539 blk)
  prep_kernel<<<7683, 256, 0, stream>>>(qdt, boxes, mask, Wq, Wk, Wv, Wo, W1, W2,
                                        bq, bk, bv, xp, xb, m8,
                                        wqkvT, woT, w1T, w2T, bqkv);
  // fused Q(scaled)/K(relayout) + V^T: 1024 + 512 blocks
  gemm_qkvt_kernel<<<1536, 256, 0, stream>>>(xb, wqkvT, bqkv, qbuf, kbuf, vtbuf);
  // attention
  attn_kernel<<<1024, 256, 0, stream>>>(qbuf, kbuf, vtbuf, m8, obuf);
  // fused tail: Wo+res -> LN1 -> FF1+relu -> FF2+res -> LN2 -> d_out
  tail_kernel<<<256, 256, 0, stream>>>(obuf, woT, w1T, w2T, xp,
                                       bo, b1, b2, g1, be1, g2, be2, (float*)d_out);
}

// Round 15
// 115.527 us; speedup vs baseline: 1.1272x; 1.1272x over previous
//
#include <hip/hip_runtime.h>
#include <hip/hip_bf16.h>

typedef unsigned short u16;
typedef unsigned int u32;
typedef __attribute__((ext_vector_type(8))) short bf16x8;   // 8 bf16 (MFMA x32 A/B frag)
typedef __attribute__((ext_vector_type(4))) float f32x4;    // MFMA C/D frag

#define BB 4
#define NN 2048
#define DD 256
#define HH 8
#define LAMBDA (-0.2550351f)  // -log2(e)/sqrt(32): folded into Q so sigmoid = rcp(1+exp2(s))

__device__ inline u16 bfu(float f) {
  __hip_bfloat16 h = __float2bfloat16(f);
  return *reinterpret_cast<u16*>(&h);
}
__device__ inline bf16x8 asfrag(uint4 v) { return __builtin_bit_cast(bf16x8, v); }

// ---------------- merged prep: x(permuted)+xb, mask->u8, weights ----------------
__global__ __launch_bounds__(256) void prep_kernel(
    const float* __restrict__ qdt, const float* __restrict__ boxes,
    const int* __restrict__ mask,
    const float* __restrict__ Wq, const float* __restrict__ Wk, const float* __restrict__ Wv,
    const float* __restrict__ Wo, const float* __restrict__ W1, const float* __restrict__ W2,
    const float* __restrict__ bq, const float* __restrict__ bk, const float* __restrict__ bv,
    float* __restrict__ xp, u16* __restrict__ xb, unsigned char* __restrict__ m8,
    u16* __restrict__ wqkvT, u16* __restrict__ woT, u16* __restrict__ w1T, u16* __restrict__ w2T,
    float* __restrict__ bqkv) {
  const int bid = blockIdx.x, t = threadIdx.x;
  if (bid < 2048) {                       // x = qdt + boxes (permuted fp32 + linear bf16)
    int i = bid * 256 + t;
    int row = i >> 6, q = i & 63;
    float4 a = ((const float4*)qdt)[i];
    float4 b = ((const float4*)boxes)[i];
    float4 v = make_float4(a.x + b.x, a.y + b.y, a.z + b.z, a.w + b.w);
    ((ushort4*)xb)[i] = make_ushort4(bfu(v.x), bfu(v.y), bfu(v.z), bfu(v.w));
    float* xr = xp + (size_t)row * 256;
    xr[((4*q+0) & 15) * 16 + ((4*q+0) >> 4)] = v.x;
    xr[((4*q+1) & 15) * 16 + ((4*q+1) >> 4)] = v.y;
    xr[((4*q+2) & 15) * 16 + ((4*q+2) >> 4)] = v.z;
    xr[((4*q+3) & 15) * 16 + ((4*q+3) >> 4)] = v.w;
  } else if (bid < 6144) {                // mask int -> u8 0/1
    int i = (bid - 2048) * 256 + t;
    int4 m = ((const int4*)mask)[i];
    ((uchar4*)m8)[i] = make_uchar4((unsigned char)m.x, (unsigned char)m.y,
                                   (unsigned char)m.z, (unsigned char)m.w);
  } else {                                // weight transposes + qkv bias concat
    int i = (bid - 6144) * 256 + t;
    if (i < 196608) {
      int n = i >> 8, k = i & 255;
      const float* src = (n < 256) ? Wq : (n < 512 ? Wk : Wv);
      wqkvT[i] = bfu(src[k * 256 + (n & 255)]);
    } else if (i < 262144) {
      int j = i - 196608; int n = j >> 8, k = j & 255;
      woT[j] = bfu(Wo[k * 256 + n]);
    } else if (i < 327680) {
      int j = i - 262144; int n = j >> 8, k = j & 255;
      w1T[j] = bfu(W1[k * 256 + n]);
    } else if (i < 393216) {
      int j = i - 327680; int n = j >> 8, k = j & 255;
      w2T[j] = bfu(W2[k * 256 + n]);
    } else if (i < 393984) {
      int n = i - 393216;
      bqkv[n] = (n < 256) ? bq[n] : (n < 512 ? bk[n - 256] : bv[n - 512]);
    }
  }
}

// ---------------- fused QKV-side GEMM: Q(scaled)+K(relayout) and V^T in one launch -------
__global__ __launch_bounds__(256) void gemm_qkvt_kernel(
    const u16* __restrict__ xb, const u16* __restrict__ wqkvT,
    const float* __restrict__ bqkv,
    u16* __restrict__ qout, u16* __restrict__ kout, u16* __restrict__ vtout) {
  __shared__ u16 At[64][264];
  __shared__ u16 Bs[64][264];
  const int bid = blockIdx.x;
  const bool isqk = bid < 1024;
  const u16* A  = isqk ? xb : (wqkvT + 512 * 256);
  const u16* Bt = isqk ? wqkvT : xb;
  const int m0 = isqk ? (bid >> 3) * 64 : ((bid - 1024) >> 7) * 64;
  const int n0 = isqk ? (bid & 7) * 64 : ((bid - 1024) & 127) * 64;
  const int t = threadIdx.x;
  {
    const int row = t >> 2, cb = (t & 3) * 64;
    const u16* ga = A  + (size_t)(m0 + row) * 256 + cb;
    const u16* gb = Bt + (size_t)(n0 + row) * 256 + cb;
#pragma unroll
    for (int i = 0; i < 8; ++i) {
      *(int4*)&At[row][cb + i * 8] = *(const int4*)(ga + i * 8);
      *(int4*)&Bs[row][cb + i * 8] = *(const int4*)(gb + i * 8);
    }
  }
  __syncthreads();
  const int w = t >> 6, l = t & 63, g = l >> 4, c = l & 15;
  f32x4 acc[4] = {};
#pragma unroll
  for (int kk = 0; kk < 256; kk += 32) {
    bf16x8 af = *(const bf16x8*)&At[w * 16 + c][kk + g * 8];
#pragma unroll
    for (int j = 0; j < 4; ++j) {
      bf16x8 bfr = *(const bf16x8*)&Bs[j * 16 + c][kk + g * 8];
      acc[j] = __builtin_amdgcn_mfma_f32_16x16x32_bf16(af, bfr, acc[j], 0, 0, 0);
    }
  }
  if (isqk) {
    if (n0 < 256) {
#pragma unroll
      for (int j = 0; j < 4; ++j)
#pragma unroll
        for (int r = 0; r < 4; ++r) {
          int m = m0 + w * 16 + g * 4 + r, n = n0 + j * 16 + c;
          qout[(size_t)m * 256 + n] = bfu((acc[j][r] + bqkv[n]) * LAMBDA);
        }
    } else {
#pragma unroll
      for (int j = 0; j < 4; ++j)
#pragma unroll
        for (int r = 0; r < 4; ++r) {
          int m = m0 + w * 16 + g * 4 + r, n = n0 + j * 16 + c;
          int ch = n - 256;
          kout[(size_t)((m >> 11) * 8 + (ch >> 5)) * 65536 + (size_t)(m & 2047) * 32 + (ch & 31)]
              = bfu(acc[j][r] + bqkv[n]);
        }
    }
  } else {
#pragma unroll
    for (int j = 0; j < 4; ++j)
#pragma unroll
      for (int r = 0; r < 4; ++r) {
        int m = m0 + w * 16 + g * 4 + r;   // channel
        int n = n0 + j * 16 + c;           // token
        vtout[(size_t)m * 8192 + n] = bfu(acc[j][r] + bqkv[512 + m]);
      }
  }
}

// ---------------- fused sigmoid-gated attention (32 q-rows per wave) ----------------
// = round-12 PASSING build (Mlds staging restored after r13's in-loop-load regression)
//   restructured so each wave owns TWO q-frags (32 q-rows): one kf read feeds 2
//   S-MFMAs, one vf read feeds 2 PV-MFMAs -> K/V LDS reads per q-row halved
//   (attn is LDS-pipe-bound: ~227cy/iter/wave of LDS issue per CU).
// block = (b, h, 128 q); 4 waves x 32 q. kv tiles of 64, dbuf, 1 barrier/tile.
// All index formulas are r12's with a +16f row offset; mask rotation invariant
// (row&7)==(c&7) holds since 32w and 16f are both 0 mod 8.
__global__ __launch_bounds__(256) void attn_kernel(
    const u16* __restrict__ qb,            // [8192][256] bf16, LAMBDA-scaled
    const u16* __restrict__ kb,            // [B][H][2048][32] bf16
    const u16* __restrict__ vtb,           // [256][8192] bf16 (V^T)
    const unsigned char* __restrict__ m8,  // [2048][2048] 0/1
    u16* __restrict__ ob) {                // [8192][256] bf16
  __shared__ u32 Klds[2][64][20];          // 16 data u32 + 4 pad (row 80 B)
  __shared__ u32 Vlds[2][32][36];          // 32 data u32 + 4 pad (row 144 B)
  __shared__ unsigned char Mlds[2][128][64];// mask tile, byte-rotated rows
  __shared__ u32 Plds[4][32][36];          // per-wave, 32 q-rows

  const int bid = blockIdx.x;
  const int qt = bid & 15, h = (bid >> 4) & 7, b = bid >> 7;
  const int q0 = qt * 128;
  const int t = threadIdx.x, w = t >> 6, l = t & 63, g = l >> 4, c = l & 15;

  // two Q B-frags: q-rows q0+32w+c and q0+32w+16+c
  const bf16x8 qf0 = asfrag(*(const uint4*)(qb + (size_t)(b * NN + q0 + 32 * w + c) * 256 + h * 32 + 8 * g));
  const bf16x8 qf1 = asfrag(*(const uint4*)(qb + (size_t)(b * NN + q0 + 32 * w + 16 + c) * 256 + h * 32 + 8 * g));
  f32x4 oacc[2][2] = {};

  const int srowK = t >> 2, ssegK = t & 3;       // K tile: 64 k-rows x 4 segs
  const int srowV = t >> 3, ssegV = t & 7;       // V^T tile: 32 d-rows x 8 segs
  const int msrow = t >> 1, mhalf = t & 1;       // mask tile: 128 q-rows x 2 halves (32B)
  const u16* kg = kb + (size_t)(b * 8 + h) * 65536 + srowK * 32 + ssegK * 8;
  const u16* vg = vtb + (size_t)(h * 32 + srowV) * 8192 + (size_t)b * NN + ssegV * 8;
  const unsigned char* mg = m8 + (size_t)(q0 + msrow) * NN + mhalf * 32;

  const int rotM = 8 * (msrow & 7);
  const int mbA0 = (32 * mhalf + rotM) & 63, mbA1 = (mbA0 + 8) & 63;
  const int mbB0 = (mbA0 + 16) & 63,         mbB1 = (mbA0 + 24) & 63;

  // prologue: stage tile 0
  uint4 krg = *(const uint4*)kg;
  uint4 vrg = *(const uint4*)vg;
  uint4 mrgA = *(const uint4*)mg;
  uint4 mrgB = *(const uint4*)(mg + 16);
  *(uint4*)&Klds[0][srowK][ssegK * 4] = krg;
  *(uint4*)&Vlds[0][srowV][ssegV * 4] = vrg;
  *(uint2*)&Mlds[0][msrow][mbA0] = make_uint2(mrgA.x, mrgA.y);
  *(uint2*)&Mlds[0][msrow][mbA1] = make_uint2(mrgA.z, mrgA.w);
  *(uint2*)&Mlds[0][msrow][mbB0] = make_uint2(mrgB.x, mrgB.y);
  *(uint2*)&Mlds[0][msrow][mbB1] = make_uint2(mrgB.z, mrgB.w);
  __syncthreads();

  const f32x4 zf = {0.f, 0.f, 0.f, 0.f};
  u32* Pw = &Plds[w][0][0];                // row stride 36 u32

  for (int it = 0; it < 32; ++it) {
    const int cur = it & 1;
    if (it < 31) {                         // prefetch tile it+1
      const int kt = (it + 1) * 64;
      krg = *(const uint4*)(kg + (size_t)kt * 32);
      vrg = *(const uint4*)(vg + kt);
      mrgA = *(const uint4*)(mg + kt);
      mrgB = *(const uint4*)(mg + kt + 16);
    }
#pragma unroll
    for (int tt = 0; tt < 4; ++tt) {
      bf16x8 kf = asfrag(*(const uint4*)&Klds[cur][16 * tt + c][4 * g]);
      f32x4 s0 = __builtin_amdgcn_mfma_f32_16x16x32_bf16(kf, qf0, zf, 0, 0, 0);
      f32x4 s1 = __builtin_amdgcn_mfma_f32_16x16x32_bf16(kf, qf1, zf, 0, 0, 0);
      const int mpos = (16 * tt + 4 * g + 8 * (c & 7)) & 63;
      u32 mdw0 = *(const u32*)&Mlds[cur][32 * w + c][mpos];
      u32 mdw1 = *(const u32*)&Mlds[cur][32 * w + 16 + c][mpos];
      // frag 0
      {
        float p0 = (float)(mdw0 & 0xffu) * __builtin_amdgcn_rcpf(1.f + __builtin_amdgcn_exp2f(s0[0]));
        float p1 = (float)((mdw0 >> 8) & 0xffu) * __builtin_amdgcn_rcpf(1.f + __builtin_amdgcn_exp2f(s0[1]));
        float p2 = (float)((mdw0 >> 16) & 0xffu) * __builtin_amdgcn_rcpf(1.f + __builtin_amdgcn_exp2f(s0[2]));
        float p3 = (float)(mdw0 >> 24) * __builtin_amdgcn_rcpf(1.f + __builtin_amdgcn_exp2f(s0[3]));
        u32 w0, w1;
        asm("v_cvt_pk_bf16_f32 %0, %1, %2" : "=v"(w0) : "v"(p0), "v"(p1));
        asm("v_cvt_pk_bf16_f32 %0, %1, %2" : "=v"(w1) : "v"(p2), "v"(p3));
        *(uint2*)&Pw[c * 36 + 8 * tt + 2 * g] = make_uint2(w0, w1);
      }
      // frag 1
      {
        float p0 = (float)(mdw1 & 0xffu) * __builtin_amdgcn_rcpf(1.f + __builtin_amdgcn_exp2f(s1[0]));
        float p1 = (float)((mdw1 >> 8) & 0xffu) * __builtin_amdgcn_rcpf(1.f + __builtin_amdgcn_exp2f(s1[1]));
        float p2 = (float)((mdw1 >> 16) & 0xffu) * __builtin_amdgcn_rcpf(1.f + __builtin_amdgcn_exp2f(s1[2]));
        float p3 = (float)(mdw1 >> 24) * __builtin_amdgcn_rcpf(1.f + __builtin_amdgcn_exp2f(s1[3]));
        u32 w0, w1;
        asm("v_cvt_pk_bf16_f32 %0, %1, %2" : "=v"(w0) : "v"(p0), "v"(p1));
        asm("v_cvt_pk_bf16_f32 %0, %1, %2" : "=v"(w1) : "v"(p2), "v"(p3));
        *(uint2*)&Pw[(16 + c) * 36 + 8 * tt + 2 * g] = make_uint2(w0, w1);
      }
    }
    // RULE-18 hard fence on wave-private P (same as r12)
    asm volatile("s_waitcnt lgkmcnt(0)" ::: "memory");
    __builtin_amdgcn_sched_barrier(0);
    // PV: one vf read feeds both P-frags
#pragma unroll
    for (int kk = 0; kk < 2; ++kk) {
      bf16x8 pf0 = asfrag(*(const uint4*)&Pw[c * 36 + 16 * kk + 4 * g]);
      bf16x8 pf1 = asfrag(*(const uint4*)&Pw[(16 + c) * 36 + 16 * kk + 4 * g]);
#pragma unroll
      for (int d0 = 0; d0 < 2; ++d0) {
        bf16x8 vf = asfrag(*(const uint4*)&Vlds[cur][16 * d0 + c][16 * kk + 4 * g]);
        oacc[0][d0] = __builtin_amdgcn_mfma_f32_16x16x32_bf16(pf0, vf, oacc[0][d0], 0, 0, 0);
        oacc[1][d0] = __builtin_amdgcn_mfma_f32_16x16x32_bf16(pf1, vf, oacc[1][d0], 0, 0, 0);
      }
    }
    if (it < 31) {
      *(uint4*)&Klds[cur ^ 1][srowK][ssegK * 4] = krg;
      *(uint4*)&Vlds[cur ^ 1][srowV][ssegV * 4] = vrg;
      *(uint2*)&Mlds[cur ^ 1][msrow][mbA0] = make_uint2(mrgA.x, mrgA.y);
      *(uint2*)&Mlds[cur ^ 1][msrow][mbA1] = make_uint2(mrgA.z, mrgA.w);
      *(uint2*)&Mlds[cur ^ 1][msrow][mbB0] = make_uint2(mrgB.x, mrgB.y);
      *(uint2*)&Mlds[cur ^ 1][msrow][mbB1] = make_uint2(mrgB.z, mrgB.w);
    }
    __syncthreads();
  }

#pragma unroll
  for (int f = 0; f < 2; ++f) {
    const size_t obase = (size_t)(b * NN + q0 + 32 * w + 16 * f) * 256 + h * 32;
#pragma unroll
    for (int d0 = 0; d0 < 2; ++d0)
#pragma unroll
      for (int r = 0; r < 4; ++r)
        ob[obase + (size_t)(4 * g + r) * 256 + 16 * d0 + c] = bfu(oacc[f][d0][r]);
  }
}

// ---------------- fused tail v3: Wo+res -> LN1 -> FF1+relu -> FF2+res -> LN2 -------------
// (unchanged from round-12 PASSING build)
__global__ __launch_bounds__(256) void tail_kernel(
    const u16* __restrict__ obuf, const u16* __restrict__ woT,
    const u16* __restrict__ w1T, const u16* __restrict__ w2T,
    const float* __restrict__ xp,          // [8192][256] f32, permuted [row][c*16+4w+j]
    const float* __restrict__ bo, const float* __restrict__ b1, const float* __restrict__ b2,
    const float* __restrict__ g1, const float* __restrict__ be1,
    const float* __restrict__ g2, const float* __restrict__ be2,
    float* __restrict__ out) {
  __shared__ u16 A[32][264];               // bf16 activation tile
  __shared__ float PS1[32][4], PS2[32][4]; // cross-wave LN partials
  const int t = threadIdx.x, w = t >> 6, l = t & 63, g = l >> 4, c = l & 15;
  const int m0 = blockIdx.x * 32;          // block's 32 rows
  const int n0 = w * 64;                   // wave's 64 cols
  const f32x4 zf4 = {0.f, 0.f, 0.f, 0.f};

  // ---- stage obuf rows m0..m0+31 (256 threads, 4 x 16B each) ----
  {
    const int srow = t >> 3, sseg = t & 7;
#pragma unroll
    for (int i = 0; i < 4; ++i) {
      uint4 v = *(const uint4*)(obuf + (size_t)(m0 + srow) * 256 + (sseg + 8 * i) * 8);
      *(uint4*)&A[srow][(sseg + 8 * i) * 8] = v;
    }
  }
  __syncthreads();

  f32x4 acc[2][4], t1[2][4];
  float mean[2][4], inv[2][4];

  // ---- GEMM1: obuf @ Wo ----
#pragma unroll
  for (int rg = 0; rg < 2; ++rg)
#pragma unroll
    for (int j = 0; j < 4; ++j) acc[rg][j] = zf4;
#pragma unroll
  for (int kk = 0; kk < 256; kk += 32) {
    bf16x8 af0 = *(const bf16x8*)&A[c][kk + 8 * g];
    bf16x8 af1 = *(const bf16x8*)&A[16 + c][kk + 8 * g];
#pragma unroll
    for (int j = 0; j < 4; ++j) {
      bf16x8 bfr = asfrag(*(const uint4*)(woT + (size_t)(n0 + 16 * j + c) * 256 + kk + 8 * g));
      acc[0][j] = __builtin_amdgcn_mfma_f32_16x16x32_bf16(af0, bfr, acc[0][j], 0, 0, 0);
      acc[1][j] = __builtin_amdgcn_mfma_f32_16x16x32_bf16(af1, bfr, acc[1][j], 0, 0, 0);
    }
  }
  // ---- epilogue1: z = acc + bo + x -> t1 regs; LN1 partials -> PS ----
  {
    float bov[4];
#pragma unroll
    for (int j = 0; j < 4; ++j) bov[j] = bo[n0 + 16 * j + c];
#pragma unroll
    for (int rg = 0; rg < 2; ++rg)
#pragma unroll
      for (int r = 0; r < 4; ++r) {
        const int rl = 16 * rg + 4 * g + r;
        float4 xq = ((const float4*)(xp + (size_t)(m0 + rl) * 256 + c * 16))[w];
        float xa[4] = {xq.x, xq.y, xq.z, xq.w};
        float a1 = 0.f, a2 = 0.f;
#pragma unroll
        for (int j = 0; j < 4; ++j) {
          float z = acc[rg][j][r] + bov[j] + xa[j];
          t1[rg][j][r] = z;
          a1 += z; a2 += z * z;
        }
#pragma unroll
        for (int off = 1; off < 16; off <<= 1) {
          a1 += __shfl_xor(a1, off);
          a2 += __shfl_xor(a2, off);
        }
        if (c == 0) { PS1[rl][w] = a1; PS2[rl][w] = a2; }
      }
  }
  __syncthreads();
#pragma unroll
  for (int rg = 0; rg < 2; ++rg)
#pragma unroll
    for (int r = 0; r < 4; ++r) {
      const int rl = 16 * rg + 4 * g + r;
      float s1 = PS1[rl][0] + PS1[rl][1] + PS1[rl][2] + PS1[rl][3];
      float s2 = PS2[rl][0] + PS2[rl][1] + PS2[rl][2] + PS2[rl][3];
      mean[rg][r] = s1 * (1.f / 256.f);
      inv[rg][r] = rsqrtf(s2 * (1.f / 256.f) - mean[rg][r] * mean[rg][r] + 1e-5f);
    }
  // normalize into t1 regs (kept for FF2 residual) + bf16 tile -> A
#pragma unroll
  for (int j = 0; j < 4; ++j) {
    const int n = n0 + 16 * j + c;
    const float gv = g1[n], bev = be1[n];
#pragma unroll
    for (int rg = 0; rg < 2; ++rg)
#pragma unroll
      for (int r = 0; r < 4; ++r) {
        float v = (t1[rg][j][r] - mean[rg][r]) * inv[rg][r] * gv + bev;
        t1[rg][j][r] = v;
        A[16 * rg + 4 * g + r][n] = bfu(v);
      }
  }
  __syncthreads();

  // ---- GEMM2: t1 @ W1, relu ----
#pragma unroll
  for (int rg = 0; rg < 2; ++rg)
#pragma unroll
    for (int j = 0; j < 4; ++j) acc[rg][j] = zf4;
#pragma unroll
  for (int kk = 0; kk < 256; kk += 32) {
    bf16x8 af0 = *(const bf16x8*)&A[c][kk + 8 * g];
    bf16x8 af1 = *(const bf16x8*)&A[16 + c][kk + 8 * g];
#pragma unroll
    for (int j = 0; j < 4; ++j) {
      bf16x8 bfr = asfrag(*(const uint4*)(w1T + (size_t)(n0 + 16 * j + c) * 256 + kk + 8 * g));
      acc[0][j] = __builtin_amdgcn_mfma_f32_16x16x32_bf16(af0, bfr, acc[0][j], 0, 0, 0);
      acc[1][j] = __builtin_amdgcn_mfma_f32_16x16x32_bf16(af1, bfr, acc[1][j], 0, 0, 0);
    }
  }
  __syncthreads();                         // all waves done reading A
#pragma unroll
  for (int j = 0; j < 4; ++j) {
    const int n = n0 + 16 * j + c;
    const float bv = b1[n];
#pragma unroll
    for (int rg = 0; rg < 2; ++rg)
#pragma unroll
      for (int r = 0; r < 4; ++r) {
        float v = acc[rg][j][r] + bv;
        A[16 * rg + 4 * g + r][n] = bfu(v > 0.f ? v : 0.f);
      }
  }
  __syncthreads();

  // ---- GEMM3: h @ W2 ----
#pragma unroll
  for (int rg = 0; rg < 2; ++rg)
#pragma unroll
    for (int j = 0; j < 4; ++j) acc[rg][j] = zf4;
#pragma unroll
  for (int kk = 0; kk < 256; kk += 32) {
    bf16x8 af0 = *(const bf16x8*)&A[c][kk + 8 * g];
    bf16x8 af1 = *(const bf16x8*)&A[16 + c][kk + 8 * g];
#pragma unroll
    for (int j = 0; j < 4; ++j) {
      bf16x8 bfr = asfrag(*(const uint4*)(w2T + (size_t)(n0 + 16 * j + c) * 256 + kk + 8 * g));
      acc[0][j] = __builtin_amdgcn_mfma_f32_16x16x32_bf16(af0, bfr, acc[0][j], 0, 0, 0);
      acc[1][j] = __builtin_amdgcn_mfma_f32_16x16x32_bf16(af1, bfr, acc[1][j], 0, 0, 0);
    }
  }
  // ---- epilogue3: z = acc + b2 + t1 (regs); LN2 -> out ----
  {
    float b2v[4];
#pragma unroll
    for (int j = 0; j < 4; ++j) b2v[j] = b2[n0 + 16 * j + c];
#pragma unroll
    for (int rg = 0; rg < 2; ++rg)
#pragma unroll
      for (int r = 0; r < 4; ++r) {
        const int rl = 16 * rg + 4 * g + r;
        float a1 = 0.f, a2 = 0.f;
#pragma unroll
        for (int j = 0; j < 4; ++j) {
          float z = acc[rg][j][r] + b2v[j] + t1[rg][j][r];
          t1[rg][j][r] = z;
          a1 += z; a2 += z * z;
        }
#pragma unroll
        for (int off = 1; off < 16; off <<= 1) {
          a1 += __shfl_xor(a1, off);
          a2 += __shfl_xor(a2, off);
        }
        if (c == 0) { PS1[rl][w] = a1; PS2[rl][w] = a2; }
      }
  }
  __syncthreads();
#pragma unroll
  for (int rg = 0; rg < 2; ++rg)
#pragma unroll
    for (int r = 0; r < 4; ++r) {
      const int rl = 16 * rg + 4 * g + r;
      float s1 = PS1[rl][0] + PS1[rl][1] + PS1[rl][2] + PS1[rl][3];
      float s2 = PS2[rl][0] + PS2[rl][1] + PS2[rl][2] + PS2[rl][3];
      mean[rg][r] = s1 * (1.f / 256.f);
      inv[rg][r] = rsqrtf(s2 * (1.f / 256.f) - mean[rg][r] * mean[rg][r] + 1e-5f);
    }
#pragma unroll
  for (int j = 0; j < 4; ++j) {
    const int n = n0 + 16 * j + c;
    const float gv = g2[n], bev = be2[n];
#pragma unroll
    for (int rg = 0; rg < 2; ++rg)
#pragma unroll
      for (int r = 0; r < 4; ++r)
        out[(size_t)(m0 + 16 * rg + 4 * g + r) * 256 + n]
            = (t1[rg][j][r] - mean[rg][r]) * inv[rg][r] * gv + bev;
  }
}

extern "C" void kernel_launch(void* const* d_in, const int* in_sizes, int n_in,
                              void* d_out, int out_size, void* d_ws, size_t ws_size,
                              hipStream_t stream) {
  const float* qdt   = (const float*)d_in[0];
  const float* boxes = (const float*)d_in[1];
  const int*   mask  = (const int*)d_in[2];
  const float* Wq = (const float*)d_in[3];
  const float* bq = (const float*)d_in[4];
  const float* Wk = (const float*)d_in[5];
  const float* bk = (const float*)d_in[6];
  const float* Wv = (const float*)d_in[7];
  const float* bv = (const float*)d_in[8];
  const float* Wo = (const float*)d_in[9];
  const float* bo = (const float*)d_in[10];
  const float* W1 = (const float*)d_in[11];
  const float* b1 = (const float*)d_in[12];
  const float* W2 = (const float*)d_in[13];
  const float* b2 = (const float*)d_in[14];
  const float* g1  = (const float*)d_in[15];
  const float* be1 = (const float*)d_in[16];
  const float* g2  = (const float*)d_in[17];
  const float* be2 = (const float*)d_in[18];

  char* ws = (char*)d_ws;
  float* xp    = (float*)(ws + 0);          // [8192,256] f32 permuted residual
  u16*   xb    = (u16*)  (ws + 8388608);
  u16*   qbuf  = (u16*)  (ws + 12582912);   // q, LAMBDA-scaled
  u16*   kbuf  = (u16*)  (ws + 16777216);   // [B][H][2048][32]
  u16*   vtbuf = (u16*)  (ws + 20971520);   // [256][8192]
  u16*   obuf  = (u16*)  (ws + 25165824);
  u16*   wqkvT = (u16*)  (ws + 46137344);   // [768,256]
  u16*   woT   = (u16*)  (ws + 46530560);
  u16*   w1T   = (u16*)  (ws + 46661632);
  u16*   w2T   = (u16*)  (ws + 46792704);
  float* bqkv  = (float*)(ws + 46923776);
  unsigned char* m8 = (unsigned char*)(ws + 46926848);  // [2048,2048] u8

  // merged prep: xp/xb (2048 blk) + mask->m8 (4096 blk) + weights (1539 blk)
  prep_kernel<<<7683, 256, 0, stream>>>(qdt, boxes, mask, Wq, Wk, Wv, Wo, W1, W2,
                                        bq, bk, bv, xp, xb, m8,
                                        wqkvT, woT, w1T, w2T, bqkv);
  // fused Q(scaled)/K(relayout) + V^T: 1024 + 512 blocks
  gemm_qkvt_kernel<<<1536, 256, 0, stream>>>(xb, wqkvT, bqkv, qbuf, kbuf, vtbuf);
  // attention: 512 blocks x (b,h,128q)
  attn_kernel<<<512, 256, 0, stream>>>(qbuf, kbuf, vtbuf, m8, obuf);
  // fused tail: Wo+res -> LN1 -> FF1+relu -> FF2+res -> LN2 -> d_out
  tail_kernel<<<256, 256, 0, stream>>>(obuf, woT, w1T, w2T, xp,
                                       bo, b1, b2, g1, be1, g2, be2, (float*)d_out);
}

// Round 16
// 115.359 us; speedup vs baseline: 1.1288x; 1.0015x over previous
//
#include <hip/hip_runtime.h>
#include <hip/hip_bf16.h>

typedef unsigned short u16;
typedef unsigned int u32;
typedef __attribute__((ext_vector_type(8))) short bf16x8;   // 8 bf16 (MFMA x32 A/B frag)
typedef __attribute__((ext_vector_type(4))) float f32x4;    // MFMA C/D frag

#define BB 4
#define NN 2048
#define DD 256
#define HH 8
#define LAMBDA (-0.2550351f)  // -log2(e)/sqrt(32): folded into Q so sigmoid = rcp(1+exp2(s))

__device__ inline u16 bfu(float f) {
  __hip_bfloat16 h = __float2bfloat16(f);
  return *reinterpret_cast<u16*>(&h);
}
__device__ inline bf16x8 asfrag(uint4 v) { return __builtin_bit_cast(bf16x8, v); }

// ---------------- merged prep: x(permuted)+xb, mask->BITS, weights ----------------
__global__ __launch_bounds__(256) void prep_kernel(
    const float* __restrict__ qdt, const float* __restrict__ boxes,
    const int* __restrict__ mask,
    const float* __restrict__ Wq, const float* __restrict__ Wk, const float* __restrict__ Wv,
    const float* __restrict__ Wo, const float* __restrict__ W1, const float* __restrict__ W2,
    const float* __restrict__ bq, const float* __restrict__ bk, const float* __restrict__ bv,
    float* __restrict__ xp, u16* __restrict__ xb, u32* __restrict__ m1,
    u16* __restrict__ wqkvT, u16* __restrict__ woT, u16* __restrict__ w1T, u16* __restrict__ w2T,
    float* __restrict__ bqkv) {
  const int bid = blockIdx.x, t = threadIdx.x;
  if (bid < 2048) {                       // x = qdt + boxes (permuted fp32 + linear bf16)
    int i = bid * 256 + t;
    int row = i >> 6, q = i & 63;
    float4 a = ((const float4*)qdt)[i];
    float4 b = ((const float4*)boxes)[i];
    float4 v = make_float4(a.x + b.x, a.y + b.y, a.z + b.z, a.w + b.w);
    ((ushort4*)xb)[i] = make_ushort4(bfu(v.x), bfu(v.y), bfu(v.z), bfu(v.w));
    float* xr = xp + (size_t)row * 256;
    xr[((4*q+0) & 15) * 16 + ((4*q+0) >> 4)] = v.x;
    xr[((4*q+1) & 15) * 16 + ((4*q+1) >> 4)] = v.y;
    xr[((4*q+2) & 15) * 16 + ((4*q+2) >> 4)] = v.z;
    xr[((4*q+3) & 15) * 16 + ((4*q+3) >> 4)] = v.w;
  } else if (bid < 2560) {                // mask: 32 ints -> 1 u32 of bits
    int i = (bid - 2048) * 256 + t;       // i in [0, 131072): m1[row][word]
    const int* src = mask + (size_t)i * 32;
    u32 bits = 0;
#pragma unroll
    for (int q4 = 0; q4 < 8; ++q4) {
      int4 m = *(const int4*)(src + q4 * 4);
      bits |= (m.x ? 1u : 0u) << (4 * q4);
      bits |= (m.y ? 1u : 0u) << (4 * q4 + 1);
      bits |= (m.z ? 1u : 0u) << (4 * q4 + 2);
      bits |= (m.w ? 1u : 0u) << (4 * q4 + 3);
    }
    m1[i] = bits;
  } else {                                // weight transposes + qkv bias concat
    int i = (bid - 2560) * 256 + t;
    if (i < 196608) {
      int n = i >> 8, k = i & 255;
      const float* src = (n < 256) ? Wq : (n < 512 ? Wk : Wv);
      wqkvT[i] = bfu(src[k * 256 + (n & 255)]);
    } else if (i < 262144) {
      int j = i - 196608; int n = j >> 8, k = j & 255;
      woT[j] = bfu(Wo[k * 256 + n]);
    } else if (i < 327680) {
      int j = i - 262144; int n = j >> 8, k = j & 255;
      w1T[j] = bfu(W1[k * 256 + n]);
    } else if (i < 393216) {
      int j = i - 327680; int n = j >> 8, k = j & 255;
      w2T[j] = bfu(W2[k * 256 + n]);
    } else if (i < 393984) {
      int n = i - 393216;
      bqkv[n] = (n < 256) ? bq[n] : (n < 512 ? bk[n - 256] : bv[n - 512]);
    }
  }
}

// ---------------- fused QKV-side GEMM: Q(scaled)+K(relayout) and V^T in one launch -------
__global__ __launch_bounds__(256) void gemm_qkvt_kernel(
    const u16* __restrict__ xb, const u16* __restrict__ wqkvT,
    const float* __restrict__ bqkv,
    u16* __restrict__ qout, u16* __restrict__ kout, u16* __restrict__ vtout) {
  __shared__ u16 At[64][264];
  __shared__ u16 Bs[64][264];
  const int bid = blockIdx.x;
  const bool isqk = bid < 1024;
  const u16* A  = isqk ? xb : (wqkvT + 512 * 256);
  const u16* Bt = isqk ? wqkvT : xb;
  const int m0 = isqk ? (bid >> 3) * 64 : ((bid - 1024) >> 7) * 64;
  const int n0 = isqk ? (bid & 7) * 64 : ((bid - 1024) & 127) * 64;
  const int t = threadIdx.x;
  {
    const int row = t >> 2, cb = (t & 3) * 64;
    const u16* ga = A  + (size_t)(m0 + row) * 256 + cb;
    const u16* gb = Bt + (size_t)(n0 + row) * 256 + cb;
#pragma unroll
    for (int i = 0; i < 8; ++i) {
      *(int4*)&At[row][cb + i * 8] = *(const int4*)(ga + i * 8);
      *(int4*)&Bs[row][cb + i * 8] = *(const int4*)(gb + i * 8);
    }
  }
  __syncthreads();
  const int w = t >> 6, l = t & 63, g = l >> 4, c = l & 15;
  f32x4 acc[4] = {};
#pragma unroll
  for (int kk = 0; kk < 256; kk += 32) {
    bf16x8 af = *(const bf16x8*)&At[w * 16 + c][kk + g * 8];
#pragma unroll
    for (int j = 0; j < 4; ++j) {
      bf16x8 bfr = *(const bf16x8*)&Bs[j * 16 + c][kk + g * 8];
      acc[j] = __builtin_amdgcn_mfma_f32_16x16x32_bf16(af, bfr, acc[j], 0, 0, 0);
    }
  }
  if (isqk) {
    if (n0 < 256) {
#pragma unroll
      for (int j = 0; j < 4; ++j)
#pragma unroll
        for (int r = 0; r < 4; ++r) {
          int m = m0 + w * 16 + g * 4 + r, n = n0 + j * 16 + c;
          qout[(size_t)m * 256 + n] = bfu((acc[j][r] + bqkv[n]) * LAMBDA);
        }
    } else {
#pragma unroll
      for (int j = 0; j < 4; ++j)
#pragma unroll
        for (int r = 0; r < 4; ++r) {
          int m = m0 + w * 16 + g * 4 + r, n = n0 + j * 16 + c;
          int ch = n - 256;
          kout[(size_t)((m >> 11) * 8 + (ch >> 5)) * 65536 + (size_t)(m & 2047) * 32 + (ch & 31)]
              = bfu(acc[j][r] + bqkv[n]);
        }
    }
  } else {
#pragma unroll
    for (int j = 0; j < 4; ++j)
#pragma unroll
      for (int r = 0; r < 4; ++r) {
        int m = m0 + w * 16 + g * 4 + r;   // channel
        int n = n0 + j * 16 + c;           // token
        vtout[(size_t)m * 8192 + n] = bfu(acc[j][r] + bqkv[512 + m]);
      }
  }
}

// ---------------- fused sigmoid-gated attention (32 q/wave, BIT mask) ----------------
// = round-14 PASSING build with ONE change: Mlds (16 KB) deleted; mask is 1
//   bit/elem in m1[2048][64] u32. Each lane register-carries its two q-rows'
//   64-bit tile masks (uint2, prefetched 1 tile ahead exactly like krg/vrg).
//   Gate: (float)((word >> (16(tt&1)+4g+r)) & 1) -- +1 VALU/elem on the
//   per-SIMD pipe, removes ALL mask traffic from the per-CU LDS pipe.
//   LDS 54.3 -> 37.9 KB => 4 blocks/CU (16 waves/CU) with r14's halved K/V reads.
__global__ __launch_bounds__(256) void attn_kernel(
    const u16* __restrict__ qb,            // [8192][256] bf16, LAMBDA-scaled
    const u16* __restrict__ kb,            // [B][H][2048][32] bf16
    const u16* __restrict__ vtb,           // [256][8192] bf16 (V^T)
    const u32* __restrict__ m1,            // [2048][64] u32 mask bits
    u16* __restrict__ ob) {                // [8192][256] bf16
  __shared__ u32 Klds[2][64][20];          // 16 data u32 + 4 pad (row 80 B)
  __shared__ u32 Vlds[2][32][36];          // 32 data u32 + 4 pad (row 144 B)
  __shared__ u32 Plds[4][32][36];          // per-wave, 32 q-rows

  const int bid = blockIdx.x;
  const int qt = bid & 15, h = (bid >> 4) & 7, b = bid >> 7;
  const int q0 = qt * 128;
  const int t = threadIdx.x, w = t >> 6, l = t & 63, g = l >> 4, c = l & 15;

  // two Q B-frags: q-rows q0+32w+c and q0+32w+16+c
  const bf16x8 qf0 = asfrag(*(const uint4*)(qb + (size_t)(b * NN + q0 + 32 * w + c) * 256 + h * 32 + 8 * g));
  const bf16x8 qf1 = asfrag(*(const uint4*)(qb + (size_t)(b * NN + q0 + 32 * w + 16 + c) * 256 + h * 32 + 8 * g));
  f32x4 oacc[2][2] = {};

  const int srowK = t >> 2, ssegK = t & 3;       // K tile: 64 k-rows x 4 segs
  const int srowV = t >> 3, ssegV = t & 7;       // V^T tile: 32 d-rows x 8 segs
  const u16* kg = kb + (size_t)(b * 8 + h) * 65536 + srowK * 32 + ssegK * 8;
  const u16* vg = vtb + (size_t)(h * 32 + srowV) * 8192 + (size_t)b * NN + ssegV * 8;
  const u32* mr0 = m1 + (size_t)(q0 + 32 * w + c) * 64;        // lane's frag0 q-row bits
  const u32* mr1 = m1 + (size_t)(q0 + 32 * w + 16 + c) * 64;   // frag1 q-row bits

  // prologue: stage tile 0
  uint4 krg = *(const uint4*)kg;
  uint4 vrg = *(const uint4*)vg;
  uint2 mc0 = *(const uint2*)mr0;          // tile-0 64-bit masks
  uint2 mc1 = *(const uint2*)mr1;
  *(uint4*)&Klds[0][srowK][ssegK * 4] = krg;
  *(uint4*)&Vlds[0][srowV][ssegV * 4] = vrg;
  __syncthreads();

  const f32x4 zf = {0.f, 0.f, 0.f, 0.f};
  u32* Pw = &Plds[w][0][0];                // row stride 36 u32

  for (int it = 0; it < 32; ++it) {
    const int cur = it & 1;
    uint2 mn0, mn1;
    if (it < 31) {                         // prefetch tile it+1 (K, V, mask bits)
      const int kt = (it + 1) * 64;
      krg = *(const uint4*)(kg + (size_t)kt * 32);
      vrg = *(const uint4*)(vg + kt);
      mn0 = *(const uint2*)(mr0 + (it + 1) * 2);
      mn1 = *(const uint2*)(mr1 + (it + 1) * 2);
    }
#pragma unroll
    for (int tt = 0; tt < 4; ++tt) {
      bf16x8 kf = asfrag(*(const uint4*)&Klds[cur][16 * tt + c][4 * g]);
      f32x4 s0 = __builtin_amdgcn_mfma_f32_16x16x32_bf16(kf, qf0, zf, 0, 0, 0);
      f32x4 s1 = __builtin_amdgcn_mfma_f32_16x16x32_bf16(kf, qf1, zf, 0, 0, 0);
      const u32 wd0 = (tt < 2) ? mc0.x : mc0.y;   // word sel is compile-time per tt
      const u32 wd1 = (tt < 2) ? mc1.x : mc1.y;
      const int off = 16 * (tt & 1) + 4 * g;      // bit offset of elem r=0
      // frag 0
      {
        float p0 = (float)((wd0 >> (off + 0)) & 1u) * __builtin_amdgcn_rcpf(1.f + __builtin_amdgcn_exp2f(s0[0]));
        float p1 = (float)((wd0 >> (off + 1)) & 1u) * __builtin_amdgcn_rcpf(1.f + __builtin_amdgcn_exp2f(s0[1]));
        float p2 = (float)((wd0 >> (off + 2)) & 1u) * __builtin_amdgcn_rcpf(1.f + __builtin_amdgcn_exp2f(s0[2]));
        float p3 = (float)((wd0 >> (off + 3)) & 1u) * __builtin_amdgcn_rcpf(1.f + __builtin_amdgcn_exp2f(s0[3]));
        u32 w0, w1;
        asm("v_cvt_pk_bf16_f32 %0, %1, %2" : "=v"(w0) : "v"(p0), "v"(p1));
        asm("v_cvt_pk_bf16_f32 %0, %1, %2" : "=v"(w1) : "v"(p2), "v"(p3));
        *(uint2*)&Pw[c * 36 + 8 * tt + 2 * g] = make_uint2(w0, w1);
      }
      // frag 1
      {
        float p0 = (float)((wd1 >> (off + 0)) & 1u) * __builtin_amdgcn_rcpf(1.f + __builtin_amdgcn_exp2f(s1[0]));
        float p1 = (float)((wd1 >> (off + 1)) & 1u) * __builtin_amdgcn_rcpf(1.f + __builtin_amdgcn_exp2f(s1[1]));
        float p2 = (float)((wd1 >> (off + 2)) & 1u) * __builtin_amdgcn_rcpf(1.f + __builtin_amdgcn_exp2f(s1[2]));
        float p3 = (float)((wd1 >> (off + 3)) & 1u) * __builtin_amdgcn_rcpf(1.f + __builtin_amdgcn_exp2f(s1[3]));
        u32 w0, w1;
        asm("v_cvt_pk_bf16_f32 %0, %1, %2" : "=v"(w0) : "v"(p0), "v"(p1));
        asm("v_cvt_pk_bf16_f32 %0, %1, %2" : "=v"(w1) : "v"(p2), "v"(p3));
        *(uint2*)&Pw[(16 + c) * 36 + 8 * tt + 2 * g] = make_uint2(w0, w1);
      }
    }
    // RULE-18 hard fence on wave-private P
    asm volatile("s_waitcnt lgkmcnt(0)" ::: "memory");
    __builtin_amdgcn_sched_barrier(0);
    // PV: one vf read feeds both P-frags
#pragma unroll
    for (int kk = 0; kk < 2; ++kk) {
      bf16x8 pf0 = asfrag(*(const uint4*)&Pw[c * 36 + 16 * kk + 4 * g]);
      bf16x8 pf1 = asfrag(*(const uint4*)&Pw[(16 + c) * 36 + 16 * kk + 4 * g]);
#pragma unroll
      for (int d0 = 0; d0 < 2; ++d0) {
        bf16x8 vf = asfrag(*(const uint4*)&Vlds[cur][16 * d0 + c][16 * kk + 4 * g]);
        oacc[0][d0] = __builtin_amdgcn_mfma_f32_16x16x32_bf16(pf0, vf, oacc[0][d0], 0, 0, 0);
        oacc[1][d0] = __builtin_amdgcn_mfma_f32_16x16x32_bf16(pf1, vf, oacc[1][d0], 0, 0, 0);
      }
    }
    if (it < 31) {
      *(uint4*)&Klds[cur ^ 1][srowK][ssegK * 4] = krg;
      *(uint4*)&Vlds[cur ^ 1][srowV][ssegV * 4] = vrg;
      mc0 = mn0; mc1 = mn1;
    }
    __syncthreads();
  }

#pragma unroll
  for (int f = 0; f < 2; ++f) {
    const size_t obase = (size_t)(b * NN + q0 + 32 * w + 16 * f) * 256 + h * 32;
#pragma unroll
    for (int d0 = 0; d0 < 2; ++d0)
#pragma unroll
      for (int r = 0; r < 4; ++r)
        ob[obase + (size_t)(4 * g + r) * 256 + 16 * d0 + c] = bfu(oacc[f][d0][r]);
  }
}

// ---------------- fused tail v3: Wo+res -> LN1 -> FF1+relu -> FF2+res -> LN2 -------------
// (unchanged from round-12 PASSING build)
__global__ __launch_bounds__(256) void tail_kernel(
    const u16* __restrict__ obuf, const u16* __restrict__ woT,
    const u16* __restrict__ w1T, const u16* __restrict__ w2T,
    const float* __restrict__ xp,          // [8192][256] f32, permuted [row][c*16+4w+j]
    const float* __restrict__ bo, const float* __restrict__ b1, const float* __restrict__ b2,
    const float* __restrict__ g1, const float* __restrict__ be1,
    const float* __restrict__ g2, const float* __restrict__ be2,
    float* __restrict__ out) {
  __shared__ u16 A[32][264];               // bf16 activation tile
  __shared__ float PS1[32][4], PS2[32][4]; // cross-wave LN partials
  const int t = threadIdx.x, w = t >> 6, l = t & 63, g = l >> 4, c = l & 15;
  const int m0 = blockIdx.x * 32;          // block's 32 rows
  const int n0 = w * 64;                   // wave's 64 cols
  const f32x4 zf4 = {0.f, 0.f, 0.f, 0.f};

  // ---- stage obuf rows m0..m0+31 (256 threads, 4 x 16B each) ----
  {
    const int srow = t >> 3, sseg = t & 7;
#pragma unroll
    for (int i = 0; i < 4; ++i) {
      uint4 v = *(const uint4*)(obuf + (size_t)(m0 + srow) * 256 + (sseg + 8 * i) * 8);
      *(uint4*)&A[srow][(sseg + 8 * i) * 8] = v;
    }
  }
  __syncthreads();

  f32x4 acc[2][4], t1[2][4];
  float mean[2][4], inv[2][4];

  // ---- GEMM1: obuf @ Wo ----
#pragma unroll
  for (int rg = 0; rg < 2; ++rg)
#pragma unroll
    for (int j = 0; j < 4; ++j) acc[rg][j] = zf4;
#pragma unroll
  for (int kk = 0; kk < 256; kk += 32) {
    bf16x8 af0 = *(const bf16x8*)&A[c][kk + 8 * g];
    bf16x8 af1 = *(const bf16x8*)&A[16 + c][kk + 8 * g];
#pragma unroll
    for (int j = 0; j < 4; ++j) {
      bf16x8 bfr = asfrag(*(const uint4*)(woT + (size_t)(n0 + 16 * j + c) * 256 + kk + 8 * g));
      acc[0][j] = __builtin_amdgcn_mfma_f32_16x16x32_bf16(af0, bfr, acc[0][j], 0, 0, 0);
      acc[1][j] = __builtin_amdgcn_mfma_f32_16x16x32_bf16(af1, bfr, acc[1][j], 0, 0, 0);
    }
  }
  // ---- epilogue1: z = acc + bo + x -> t1 regs; LN1 partials -> PS ----
  {
    float bov[4];
#pragma unroll
    for (int j = 0; j < 4; ++j) bov[j] = bo[n0 + 16 * j + c];
#pragma unroll
    for (int rg = 0; rg < 2; ++rg)
#pragma unroll
      for (int r = 0; r < 4; ++r) {
        const int rl = 16 * rg + 4 * g + r;
        float4 xq = ((const float4*)(xp + (size_t)(m0 + rl) * 256 + c * 16))[w];
        float xa[4] = {xq.x, xq.y, xq.z, xq.w};
        float a1 = 0.f, a2 = 0.f;
#pragma unroll
        for (int j = 0; j < 4; ++j) {
          float z = acc[rg][j][r] + bov[j] + xa[j];
          t1[rg][j][r] = z;
          a1 += z; a2 += z * z;
        }
#pragma unroll
        for (int off = 1; off < 16; off <<= 1) {
          a1 += __shfl_xor(a1, off);
          a2 += __shfl_xor(a2, off);
        }
        if (c == 0) { PS1[rl][w] = a1; PS2[rl][w] = a2; }
      }
  }
  __syncthreads();
#pragma unroll
  for (int rg = 0; rg < 2; ++rg)
#pragma unroll
    for (int r = 0; r < 4; ++r) {
      const int rl = 16 * rg + 4 * g + r;
      float s1 = PS1[rl][0] + PS1[rl][1] + PS1[rl][2] + PS1[rl][3];
      float s2 = PS2[rl][0] + PS2[rl][1] + PS2[rl][2] + PS2[rl][3];
      mean[rg][r] = s1 * (1.f / 256.f);
      inv[rg][r] = rsqrtf(s2 * (1.f / 256.f) - mean[rg][r] * mean[rg][r] + 1e-5f);
    }
  // normalize into t1 regs (kept for FF2 residual) + bf16 tile -> A
#pragma unroll
  for (int j = 0; j < 4; ++j) {
    const int n = n0 + 16 * j + c;
    const float gv = g1[n], bev = be1[n];
#pragma unroll
    for (int rg = 0; rg < 2; ++rg)
#pragma unroll
      for (int r = 0; r < 4; ++r) {
        float v = (t1[rg][j][r] - mean[rg][r]) * inv[rg][r] * gv + bev;
        t1[rg][j][r] = v;
        A[16 * rg + 4 * g + r][n] = bfu(v);
      }
  }
  __syncthreads();

  // ---- GEMM2: t1 @ W1, relu ----
#pragma unroll
  for (int rg = 0; rg < 2; ++rg)
#pragma unroll
    for (int j = 0; j < 4; ++j) acc[rg][j] = zf4;
#pragma unroll
  for (int kk = 0; kk < 256; kk += 32) {
    bf16x8 af0 = *(const bf16x8*)&A[c][kk + 8 * g];
    bf16x8 af1 = *(const bf16x8*)&A[16 + c][kk + 8 * g];
#pragma unroll
    for (int j = 0; j < 4; ++j) {
      bf16x8 bfr = asfrag(*(const uint4*)(w1T + (size_t)(n0 + 16 * j + c) * 256 + kk + 8 * g));
      acc[0][j] = __builtin_amdgcn_mfma_f32_16x16x32_bf16(af0, bfr, acc[0][j], 0, 0, 0);
      acc[1][j] = __builtin_amdgcn_mfma_f32_16x16x32_bf16(af1, bfr, acc[1][j], 0, 0, 0);
    }
  }
  __syncthreads();                         // all waves done reading A
#pragma unroll
  for (int j = 0; j < 4; ++j) {
    const int n = n0 + 16 * j + c;
    const float bv = b1[n];
#pragma unroll
    for (int rg = 0; rg < 2; ++rg)
#pragma unroll
      for (int r = 0; r < 4; ++r) {
        float v = acc[rg][j][r] + bv;
        A[16 * rg + 4 * g + r][n] = bfu(v > 0.f ? v : 0.f);
      }
  }
  __syncthreads();

  // ---- GEMM3: h @ W2 ----
#pragma unroll
  for (int rg = 0; rg < 2; ++rg)
#pragma unroll
    for (int j = 0; j < 4; ++j) acc[rg][j] = zf4;
#pragma unroll
  for (int kk = 0; kk < 256; kk += 32) {
    bf16x8 af0 = *(const bf16x8*)&A[c][kk + 8 * g];
    bf16x8 af1 = *(const bf16x8*)&A[16 + c][kk + 8 * g];
#pragma unroll
    for (int j = 0; j < 4; ++j) {
      bf16x8 bfr = asfrag(*(const uint4*)(w2T + (size_t)(n0 + 16 * j + c) * 256 + kk + 8 * g));
      acc[0][j] = __builtin_amdgcn_mfma_f32_16x16x32_bf16(af0, bfr, acc[0][j], 0, 0, 0);
      acc[1][j] = __builtin_amdgcn_mfma_f32_16x16x32_bf16(af1, bfr, acc[1][j], 0, 0, 0);
    }
  }
  // ---- epilogue3: z = acc + b2 + t1 (regs); LN2 -> out ----
  {
    float b2v[4];
#pragma unroll
    for (int j = 0; j < 4; ++j) b2v[j] = b2[n0 + 16 * j + c];
#pragma unroll
    for (int rg = 0; rg < 2; ++rg)
#pragma unroll
      for (int r = 0; r < 4; ++r) {
        const int rl = 16 * rg + 4 * g + r;
        float a1 = 0.f, a2 = 0.f;
#pragma unroll
        for (int j = 0; j < 4; ++j) {
          float z = acc[rg][j][r] + b2v[j] + t1[rg][j][r];
          t1[rg][j][r] = z;
          a1 += z; a2 += z * z;
        }
#pragma unroll
        for (int off = 1; off < 16; off <<= 1) {
          a1 += __shfl_xor(a1, off);
          a2 += __shfl_xor(a2, off);
        }
        if (c == 0) { PS1[rl][w] = a1; PS2[rl][w] = a2; }
      }
  }
  __syncthreads();
#pragma unroll
  for (int rg = 0; rg < 2; ++rg)
#pragma unroll
    for (int r = 0; r < 4; ++r) {
      const int rl = 16 * rg + 4 * g + r;
      float s1 = PS1[rl][0] + PS1[rl][1] + PS1[rl][2] + PS1[rl][3];
      float s2 = PS2[rl][0] + PS2[rl][1] + PS2[rl][2] + PS2[rl][3];
      mean[rg][r] = s1 * (1.f / 256.f);
      inv[rg][r] = rsqrtf(s2 * (1.f / 256.f) - mean[rg][r] * mean[rg][r] + 1e-5f);
    }
#pragma unroll
  for (int j = 0; j < 4; ++j) {
    const int n = n0 + 16 * j + c;
    const float gv = g2[n], bev = be2[n];
#pragma unroll
    for (int rg = 0; rg < 2; ++rg)
#pragma unroll
      for (int r = 0; r < 4; ++r)
        out[(size_t)(m0 + 16 * rg + 4 * g + r) * 256 + n]
            = (t1[rg][j][r] - mean[rg][r]) * inv[rg][r] * gv + bev;
  }
}

extern "C" void kernel_launch(void* const* d_in, const int* in_sizes, int n_in,
                              void* d_out, int out_size, void* d_ws, size_t ws_size,
                              hipStream_t stream) {
  const float* qdt   = (const float*)d_in[0];
  const float* boxes = (const float*)d_in[1];
  const int*   mask  = (const int*)d_in[2];
  const float* Wq = (const float*)d_in[3];
  const float* bq = (const float*)d_in[4];
  const float* Wk = (const float*)d_in[5];
  const float* bk = (const float*)d_in[6];
  const float* Wv = (const float*)d_in[7];
  const float* bv = (const float*)d_in[8];
  const float* Wo = (const float*)d_in[9];
  const float* bo = (const float*)d_in[10];
  const float* W1 = (const float*)d_in[11];
  const float* b1 = (const float*)d_in[12];
  const float* W2 = (const float*)d_in[13];
  const float* b2 = (const float*)d_in[14];
  const float* g1  = (const float*)d_in[15];
  const float* be1 = (const float*)d_in[16];
  const float* g2  = (const float*)d_in[17];
  const float* be2 = (const float*)d_in[18];

  char* ws = (char*)d_ws;
  float* xp    = (float*)(ws + 0);          // [8192,256] f32 permuted residual
  u16*   xb    = (u16*)  (ws + 8388608);
  u16*   qbuf  = (u16*)  (ws + 12582912);   // q, LAMBDA-scaled
  u16*   kbuf  = (u16*)  (ws + 16777216);   // [B][H][2048][32]
  u16*   vtbuf = (u16*)  (ws + 20971520);   // [256][8192]
  u16*   obuf  = (u16*)  (ws + 25165824);
  u16*   wqkvT = (u16*)  (ws + 46137344);   // [768,256]
  u16*   woT   = (u16*)  (ws + 46530560);
  u16*   w1T   = (u16*)  (ws + 46661632);
  u16*   w2T   = (u16*)  (ws + 46792704);
  float* bqkv  = (float*)(ws + 46923776);
  u32*   m1    = (u32*)  (ws + 46926848);   // [2048][64] u32 mask bits (512 KB)

  // merged prep: xp/xb (2048) + mask-bits (512) + weights (1539) = 4099 blocks
  prep_kernel<<<4099, 256, 0, stream>>>(qdt, boxes, mask, Wq, Wk, Wv, Wo, W1, W2,
                                        bq, bk, bv, xp, xb, m1,
                                        wqkvT, woT, w1T, w2T, bqkv);
  // fused Q(scaled)/K(relayout) + V^T: 1024 + 512 blocks
  gemm_qkvt_kernel<<<1536, 256, 0, stream>>>(xb, wqkvT, bqkv, qbuf, kbuf, vtbuf);
  // attention: 512 blocks x (b,h,128q)
  attn_kernel<<<512, 256, 0, stream>>>(qbuf, kbuf, vtbuf, m1, obuf);
  // fused tail: Wo+res -> LN1 -> FF1+relu -> FF2+res -> LN2 -> d_out
  tail_kernel<<<256, 256, 0, stream>>>(obuf, woT, w1T, w2T, xp,
                                       bo, b1, b2, g1, be1, g2, be2, (float*)d_out);
}

// Round 17
// 110.966 us; speedup vs baseline: 1.1735x; 1.0396x over previous
//
#include <hip/hip_runtime.h>
#include <hip/hip_bf16.h>

typedef unsigned short u16;
typedef unsigned int u32;
typedef __attribute__((ext_vector_type(8))) short bf16x8;   // 8 bf16 (MFMA x32 A/B frag)
typedef __attribute__((ext_vector_type(4))) float f32x4;    // MFMA C/D frag

#define BB 4
#define NN 2048
#define DD 256
#define HH 8
#define LAMBDA (-0.2550351f)  // -log2(e)/sqrt(32): folded into Q so sigmoid = rcp(1+exp2(s))

__device__ inline u16 bfu(float f) {
  __hip_bfloat16 h = __float2bfloat16(f);
  return *reinterpret_cast<u16*>(&h);
}
__device__ inline bf16x8 asfrag(uint4 v) { return __builtin_bit_cast(bf16x8, v); }

// ---------------- merged prep: x(permuted)+xb, mask->BITS, weights ----------------
__global__ __launch_bounds__(256) void prep_kernel(
    const float* __restrict__ qdt, const float* __restrict__ boxes,
    const int* __restrict__ mask,
    const float* __restrict__ Wq, const float* __restrict__ Wk, const float* __restrict__ Wv,
    const float* __restrict__ Wo, const float* __restrict__ W1, const float* __restrict__ W2,
    const float* __restrict__ bq, const float* __restrict__ bk, const float* __restrict__ bv,
    float* __restrict__ xp, u16* __restrict__ xb, u32* __restrict__ m1,
    u16* __restrict__ wqkvT, u16* __restrict__ woT, u16* __restrict__ w1T, u16* __restrict__ w2T,
    float* __restrict__ bqkv) {
  const int bid = blockIdx.x, t = threadIdx.x;
  if (bid < 2048) {                       // x = qdt + boxes (permuted fp32 + linear bf16)
    int i = bid * 256 + t;
    int row = i >> 6, q = i & 63;
    float4 a = ((const float4*)qdt)[i];
    float4 b = ((const float4*)boxes)[i];
    float4 v = make_float4(a.x + b.x, a.y + b.y, a.z + b.z, a.w + b.w);
    ((ushort4*)xb)[i] = make_ushort4(bfu(v.x), bfu(v.y), bfu(v.z), bfu(v.w));
    float* xr = xp + (size_t)row * 256;
    xr[((4*q+0) & 15) * 16 + ((4*q+0) >> 4)] = v.x;
    xr[((4*q+1) & 15) * 16 + ((4*q+1) >> 4)] = v.y;
    xr[((4*q+2) & 15) * 16 + ((4*q+2) >> 4)] = v.z;
    xr[((4*q+3) & 15) * 16 + ((4*q+3) >> 4)] = v.w;
  } else if (bid < 2560) {                // mask: 32 ints -> 1 u32 of bits
    int i = (bid - 2048) * 256 + t;       // i in [0, 131072): m1[row][word]
    const int* src = mask + (size_t)i * 32;
    u32 bits = 0;
#pragma unroll
    for (int q4 = 0; q4 < 8; ++q4) {
      int4 m = *(const int4*)(src + q4 * 4);
      bits |= (m.x ? 1u : 0u) << (4 * q4);
      bits |= (m.y ? 1u : 0u) << (4 * q4 + 1);
      bits |= (m.z ? 1u : 0u) << (4 * q4 + 2);
      bits |= (m.w ? 1u : 0u) << (4 * q4 + 3);
    }
    m1[i] = bits;
  } else {                                // weight transposes + qkv bias concat
    int i = (bid - 2560) * 256 + t;
    if (i < 196608) {
      int n = i >> 8, k = i & 255;
      const float* src = (n < 256) ? Wq : (n < 512 ? Wk : Wv);
      wqkvT[i] = bfu(src[k * 256 + (n & 255)]);
    } else if (i < 262144) {
      int j = i - 196608; int n = j >> 8, k = j & 255;
      woT[j] = bfu(Wo[k * 256 + n]);
    } else if (i < 327680) {
      int j = i - 262144; int n = j >> 8, k = j & 255;
      w1T[j] = bfu(W1[k * 256 + n]);
    } else if (i < 393216) {
      int j = i - 327680; int n = j >> 8, k = j & 255;
      w2T[j] = bfu(W2[k * 256 + n]);
    } else if (i < 393984) {
      int n = i - 393216;
      bqkv[n] = (n < 256) ? bq[n] : (n < 512 ? bk[n - 256] : bv[n - 512]);
    }
  }
}

// ---------------- fused QKV-side GEMM: Q(scaled)+K(relayout) and V^T in one launch -------
__global__ __launch_bounds__(256) void gemm_qkvt_kernel(
    const u16* __restrict__ xb, const u16* __restrict__ wqkvT,
    const float* __restrict__ bqkv,
    u16* __restrict__ qout, u16* __restrict__ kout, u16* __restrict__ vtout) {
  __shared__ u16 At[64][264];
  __shared__ u16 Bs[64][264];
  const int bid = blockIdx.x;
  const bool isqk = bid < 1024;
  const u16* A  = isqk ? xb : (wqkvT + 512 * 256);
  const u16* Bt = isqk ? wqkvT : xb;
  const int m0 = isqk ? (bid >> 3) * 64 : ((bid - 1024) >> 7) * 64;
  const int n0 = isqk ? (bid & 7) * 64 : ((bid - 1024) & 127) * 64;
  const int t = threadIdx.x;
  {
    const int row = t >> 2, cb = (t & 3) * 64;
    const u16* ga = A  + (size_t)(m0 + row) * 256 + cb;
    const u16* gb = Bt + (size_t)(n0 + row) * 256 + cb;
#pragma unroll
    for (int i = 0; i < 8; ++i) {
      *(int4*)&At[row][cb + i * 8] = *(const int4*)(ga + i * 8);
      *(int4*)&Bs[row][cb + i * 8] = *(const int4*)(gb + i * 8);
    }
  }
  __syncthreads();
  const int w = t >> 6, l = t & 63, g = l >> 4, c = l & 15;
  f32x4 acc[4] = {};
#pragma unroll
  for (int kk = 0; kk < 256; kk += 32) {
    bf16x8 af = *(const bf16x8*)&At[w * 16 + c][kk + g * 8];
#pragma unroll
    for (int j = 0; j < 4; ++j) {
      bf16x8 bfr = *(const bf16x8*)&Bs[j * 16 + c][kk + g * 8];
      acc[j] = __builtin_amdgcn_mfma_f32_16x16x32_bf16(af, bfr, acc[j], 0, 0, 0);
    }
  }
  if (isqk) {
    if (n0 < 256) {
#pragma unroll
      for (int j = 0; j < 4; ++j)
#pragma unroll
        for (int r = 0; r < 4; ++r) {
          int m = m0 + w * 16 + g * 4 + r, n = n0 + j * 16 + c;
          qout[(size_t)m * 256 + n] = bfu((acc[j][r] + bqkv[n]) * LAMBDA);
        }
    } else {
#pragma unroll
      for (int j = 0; j < 4; ++j)
#pragma unroll
        for (int r = 0; r < 4; ++r) {
          int m = m0 + w * 16 + g * 4 + r, n = n0 + j * 16 + c;
          int ch = n - 256;
          kout[(size_t)((m >> 11) * 8 + (ch >> 5)) * 65536 + (size_t)(m & 2047) * 32 + (ch & 31)]
              = bfu(acc[j][r] + bqkv[n]);
        }
    }
  } else {
#pragma unroll
    for (int j = 0; j < 4; ++j)
#pragma unroll
      for (int r = 0; r < 4; ++r) {
        int m = m0 + w * 16 + g * 4 + r;   // channel
        int n = n0 + j * 16 + c;           // token
        vtout[(size_t)m * 8192 + n] = bfu(acc[j][r] + bqkv[512 + m]);
      }
  }
}

// ---------------- fused sigmoid-gated attention (r12 geometry + r15 bitmask) -------------
// r12 (PASSING, 59.7us): block (b,h,64q), 4 waves x 16q, 1024 blocks = 16 waves/CU.
// r15 (PASSING): mask = 1 bit/elem, register-carried uint2/lane, prefetched like krg/vrg.
// Combination deletes Mlds + all mask LDS ops from the per-CU LDS pipe:
// LDS 36.9 -> 28.7 KB, per-iter LDS issue ~232 -> ~172 cy/wave.
__global__ __launch_bounds__(256) void attn_kernel(
    const u16* __restrict__ qb,            // [8192][256] bf16, LAMBDA-scaled
    const u16* __restrict__ kb,            // [B][H][2048][32] bf16
    const u16* __restrict__ vtb,           // [256][8192] bf16 (V^T)
    const u32* __restrict__ m1,            // [2048][64] u32 mask bits
    u16* __restrict__ ob) {                // [8192][256] bf16
  __shared__ u32 Klds[2][64][20];          // 16 data u32 + 4 pad (row 80 B)
  __shared__ u32 Vlds[2][32][36];          // 32 data u32 + 4 pad (row 144 B)
  __shared__ u32 Plds[4][16][36];          // 32 data u32 + 4 pad, per-wave

  const int bid = blockIdx.x;
  const int qt = bid & 31, h = (bid >> 5) & 7, b = bid >> 8;
  const int q0 = qt * 64;
  const int t = threadIdx.x, w = t >> 6, l = t & 63, g = l >> 4, c = l & 15;

  const bf16x8 qf = asfrag(*(const uint4*)(qb + (size_t)(b * NN + q0 + 16 * w + c) * 256 + h * 32 + 8 * g));
  f32x4 oacc[2] = {};

  const int srowK = t >> 2, ssegK = t & 3;
  const int srowV = t >> 3, ssegV = t & 7;
  const u16* kg = kb + (size_t)(b * 8 + h) * 65536 + srowK * 32 + ssegK * 8;
  const u16* vg = vtb + (size_t)(h * 32 + srowV) * 8192 + (size_t)b * NN + ssegV * 8;
  const u32* mr = m1 + (size_t)(q0 + 16 * w + c) * 64;   // lane's q-row bit words

  uint4 krg = *(const uint4*)kg;
  uint4 vrg = *(const uint4*)vg;
  uint2 mc = *(const uint2*)mr;            // tile-0 64-bit mask for this q-row
  *(uint4*)&Klds[0][srowK][ssegK * 4] = krg;
  *(uint4*)&Vlds[0][srowV][ssegV * 4] = vrg;
  __syncthreads();

  const f32x4 zf = {0.f, 0.f, 0.f, 0.f};
  u32* Pw = &Plds[w][0][0];

  for (int it = 0; it < 32; ++it) {
    const int cur = it & 1;
    uint2 mn;
    if (it < 31) {                         // prefetch tile it+1 (K, V, mask bits)
      const int kt = (it + 1) * 64;
      krg = *(const uint4*)(kg + (size_t)kt * 32);
      vrg = *(const uint4*)(vg + kt);
      mn = *(const uint2*)(mr + (it + 1) * 2);
    }
#pragma unroll
    for (int tt = 0; tt < 4; ++tt) {
      bf16x8 kf = asfrag(*(const uint4*)&Klds[cur][16 * tt + c][4 * g]);
      f32x4 s = __builtin_amdgcn_mfma_f32_16x16x32_bf16(kf, qf, zf, 0, 0, 0);
      const u32 wd = (tt < 2) ? mc.x : mc.y;   // word sel compile-time per tt
      const int off = 16 * (tt & 1) + 4 * g;   // bit offset of elem r=0
      float p0 = (float)((wd >> (off + 0)) & 1u) * __builtin_amdgcn_rcpf(1.f + __builtin_amdgcn_exp2f(s[0]));
      float p1 = (float)((wd >> (off + 1)) & 1u) * __builtin_amdgcn_rcpf(1.f + __builtin_amdgcn_exp2f(s[1]));
      float p2 = (float)((wd >> (off + 2)) & 1u) * __builtin_amdgcn_rcpf(1.f + __builtin_amdgcn_exp2f(s[2]));
      float p3 = (float)((wd >> (off + 3)) & 1u) * __builtin_amdgcn_rcpf(1.f + __builtin_amdgcn_exp2f(s[3]));
      u32 w0, w1;
      asm("v_cvt_pk_bf16_f32 %0, %1, %2" : "=v"(w0) : "v"(p0), "v"(p1));
      asm("v_cvt_pk_bf16_f32 %0, %1, %2" : "=v"(w1) : "v"(p2), "v"(p3));
      *(uint2*)&Pw[c * 36 + 8 * tt + 2 * g] = make_uint2(w0, w1);
    }
    // RULE-18 hard fence on wave-private P
    asm volatile("s_waitcnt lgkmcnt(0)" ::: "memory");
    __builtin_amdgcn_sched_barrier(0);
#pragma unroll
    for (int kk = 0; kk < 2; ++kk) {
      bf16x8 pf = asfrag(*(const uint4*)&Pw[c * 36 + 16 * kk + 4 * g]);
#pragma unroll
      for (int d0 = 0; d0 < 2; ++d0) {
        bf16x8 vf = asfrag(*(const uint4*)&Vlds[cur][16 * d0 + c][16 * kk + 4 * g]);
        oacc[d0] = __builtin_amdgcn_mfma_f32_16x16x32_bf16(pf, vf, oacc[d0], 0, 0, 0);
      }
    }
    if (it < 31) {
      *(uint4*)&Klds[cur ^ 1][srowK][ssegK * 4] = krg;
      *(uint4*)&Vlds[cur ^ 1][srowV][ssegV * 4] = vrg;
      mc = mn;
    }
    __syncthreads();
  }

  const size_t obase = (size_t)(b * NN + q0 + 16 * w) * 256 + h * 32;
#pragma unroll
  for (int d0 = 0; d0 < 2; ++d0)
#pragma unroll
    for (int r = 0; r < 4; ++r)
      ob[obase + (size_t)(4 * g + r) * 256 + 16 * d0 + c] = bfu(oacc[d0][r]);
}

// ---------------- fused tail v3: Wo+res -> LN1 -> FF1+relu -> FF2+res -> LN2 -------------
// (unchanged from round-12 PASSING build)
__global__ __launch_bounds__(256) void tail_kernel(
    const u16* __restrict__ obuf, const u16* __restrict__ woT,
    const u16* __restrict__ w1T, const u16* __restrict__ w2T,
    const float* __restrict__ xp,          // [8192][256] f32, permuted [row][c*16+4w+j]
    const float* __restrict__ bo, const float* __restrict__ b1, const float* __restrict__ b2,
    const float* __restrict__ g1, const float* __restrict__ be1,
    const float* __restrict__ g2, const float* __restrict__ be2,
    float* __restrict__ out) {
  __shared__ u16 A[32][264];               // bf16 activation tile
  __shared__ float PS1[32][4], PS2[32][4]; // cross-wave LN partials
  const int t = threadIdx.x, w = t >> 6, l = t & 63, g = l >> 4, c = l & 15;
  const int m0 = blockIdx.x * 32;          // block's 32 rows
  const int n0 = w * 64;                   // wave's 64 cols
  const f32x4 zf4 = {0.f, 0.f, 0.f, 0.f};

  // ---- stage obuf rows m0..m0+31 (256 threads, 4 x 16B each) ----
  {
    const int srow = t >> 3, sseg = t & 7;
#pragma unroll
    for (int i = 0; i < 4; ++i) {
      uint4 v = *(const uint4*)(obuf + (size_t)(m0 + srow) * 256 + (sseg + 8 * i) * 8);
      *(uint4*)&A[srow][(sseg + 8 * i) * 8] = v;
    }
  }
  __syncthreads();

  f32x4 acc[2][4], t1[2][4];
  float mean[2][4], inv[2][4];

  // ---- GEMM1: obuf @ Wo ----
#pragma unroll
  for (int rg = 0; rg < 2; ++rg)
#pragma unroll
    for (int j = 0; j < 4; ++j) acc[rg][j] = zf4;
#pragma unroll
  for (int kk = 0; kk < 256; kk += 32) {
    bf16x8 af0 = *(const bf16x8*)&A[c][kk + 8 * g];
    bf16x8 af1 = *(const bf16x8*)&A[16 + c][kk + 8 * g];
#pragma unroll
    for (int j = 0; j < 4; ++j) {
      bf16x8 bfr = asfrag(*(const uint4*)(woT + (size_t)(n0 + 16 * j + c) * 256 + kk + 8 * g));
      acc[0][j] = __builtin_amdgcn_mfma_f32_16x16x32_bf16(af0, bfr, acc[0][j], 0, 0, 0);
      acc[1][j] = __builtin_amdgcn_mfma_f32_16x16x32_bf16(af1, bfr, acc[1][j], 0, 0, 0);
    }
  }
  // ---- epilogue1: z = acc + bo + x -> t1 regs; LN1 partials -> PS ----
  {
    float bov[4];
#pragma unroll
    for (int j = 0; j < 4; ++j) bov[j] = bo[n0 + 16 * j + c];
#pragma unroll
    for (int rg = 0; rg < 2; ++rg)
#pragma unroll
      for (int r = 0; r < 4; ++r) {
        const int rl = 16 * rg + 4 * g + r;
        float4 xq = ((const float4*)(xp + (size_t)(m0 + rl) * 256 + c * 16))[w];
        float xa[4] = {xq.x, xq.y, xq.z, xq.w};
        float a1 = 0.f, a2 = 0.f;
#pragma unroll
        for (int j = 0; j < 4; ++j) {
          float z = acc[rg][j][r] + bov[j] + xa[j];
          t1[rg][j][r] = z;
          a1 += z; a2 += z * z;
        }
#pragma unroll
        for (int off = 1; off < 16; off <<= 1) {
          a1 += __shfl_xor(a1, off);
          a2 += __shfl_xor(a2, off);
        }
        if (c == 0) { PS1[rl][w] = a1; PS2[rl][w] = a2; }
      }
  }
  __syncthreads();
#pragma unroll
  for (int rg = 0; rg < 2; ++rg)
#pragma unroll
    for (int r = 0; r < 4; ++r) {
      const int rl = 16 * rg + 4 * g + r;
      float s1 = PS1[rl][0] + PS1[rl][1] + PS1[rl][2] + PS1[rl][3];
      float s2 = PS2[rl][0] + PS2[rl][1] + PS2[rl][2] + PS2[rl][3];
      mean[rg][r] = s1 * (1.f / 256.f);
      inv[rg][r] = rsqrtf(s2 * (1.f / 256.f) - mean[rg][r] * mean[rg][r] + 1e-5f);
    }
  // normalize into t1 regs (kept for FF2 residual) + bf16 tile -> A
#pragma unroll
  for (int j = 0; j < 4; ++j) {
    const int n = n0 + 16 * j + c;
    const float gv = g1[n], bev = be1[n];
#pragma unroll
    for (int rg = 0; rg < 2; ++rg)
#pragma unroll
      for (int r = 0; r < 4; ++r) {
        float v = (t1[rg][j][r] - mean[rg][r]) * inv[rg][r] * gv + bev;
        t1[rg][j][r] = v;
        A[16 * rg + 4 * g + r][n] = bfu(v);
      }
  }
  __syncthreads();

  // ---- GEMM2: t1 @ W1, relu ----
#pragma unroll
  for (int rg = 0; rg < 2; ++rg)
#pragma unroll
    for (int j = 0; j < 4; ++j) acc[rg][j] = zf4;
#pragma unroll
  for (int kk = 0; kk < 256; kk += 32) {
    bf16x8 af0 = *(const bf16x8*)&A[c][kk + 8 * g];
    bf16x8 af1 = *(const bf16x8*)&A[16 + c][kk + 8 * g];
#pragma unroll
    for (int j = 0; j < 4; ++j) {
      bf16x8 bfr = asfrag(*(const uint4*)(w1T + (size_t)(n0 + 16 * j + c) * 256 + kk + 8 * g));
      acc[0][j] = __builtin_amdgcn_mfma_f32_16x16x32_bf16(af0, bfr, acc[0][j], 0, 0, 0);
      acc[1][j] = __builtin_amdgcn_mfma_f32_16x16x32_bf16(af1, bfr, acc[1][j], 0, 0, 0);
    }
  }
  __syncthreads();                         // all waves done reading A
#pragma unroll
  for (int j = 0; j < 4; ++j) {
    const int n = n0 + 16 * j + c;
    const float bv = b1[n];
#pragma unroll
    for (int rg = 0; rg < 2; ++rg)
#pragma unroll
      for (int r = 0; r < 4; ++r) {
        float v = acc[rg][j][r] + bv;
        A[16 * rg + 4 * g + r][n] = bfu(v > 0.f ? v : 0.f);
      }
  }
  __syncthreads();

  // ---- GEMM3: h @ W2 ----
#pragma unroll
  for (int rg = 0; rg < 2; ++rg)
#pragma unroll
    for (int j = 0; j < 4; ++j) acc[rg][j] = zf4;
#pragma unroll
  for (int kk = 0; kk < 256; kk += 32) {
    bf16x8 af0 = *(const bf16x8*)&A[c][kk + 8 * g];
    bf16x8 af1 = *(const bf16x8*)&A[16 + c][kk + 8 * g];
#pragma unroll
    for (int j = 0; j < 4; ++j) {
      bf16x8 bfr = asfrag(*(const uint4*)(w2T + (size_t)(n0 + 16 * j + c) * 256 + kk + 8 * g));
      acc[0][j] = __builtin_amdgcn_mfma_f32_16x16x32_bf16(af0, bfr, acc[0][j], 0, 0, 0);
      acc[1][j] = __builtin_amdgcn_mfma_f32_16x16x32_bf16(af1, bfr, acc[1][j], 0, 0, 0);
    }
  }
  // ---- epilogue3: z = acc + b2 + t1 (regs); LN2 -> out ----
  {
    float b2v[4];
#pragma unroll
    for (int j = 0; j < 4; ++j) b2v[j] = b2[n0 + 16 * j + c];
#pragma unroll
    for (int rg = 0; rg < 2; ++rg)
#pragma unroll
      for (int r = 0; r < 4; ++r) {
        const int rl = 16 * rg + 4 * g + r;
        float a1 = 0.f, a2 = 0.f;
#pragma unroll
        for (int j = 0; j < 4; ++j) {
          float z = acc[rg][j][r] + b2v[j] + t1[rg][j][r];
          t1[rg][j][r] = z;
          a1 += z; a2 += z * z;
        }
#pragma unroll
        for (int off = 1; off < 16; off <<= 1) {
          a1 += __shfl_xor(a1, off);
          a2 += __shfl_xor(a2, off);
        }
        if (c == 0) { PS1[rl][w] = a1; PS2[rl][w] = a2; }
      }
  }
  __syncthreads();
#pragma unroll
  for (int rg = 0; rg < 2; ++rg)
#pragma unroll
    for (int r = 0; r < 4; ++r) {
      const int rl = 16 * rg + 4 * g + r;
      float s1 = PS1[rl][0] + PS1[rl][1] + PS1[rl][2] + PS1[rl][3];
      float s2 = PS2[rl][0] + PS2[rl][1] + PS2[rl][2] + PS2[rl][3];
      mean[rg][r] = s1 * (1.f / 256.f);
      inv[rg][r] = rsqrtf(s2 * (1.f / 256.f) - mean[rg][r] * mean[rg][r] + 1e-5f);
    }
#pragma unroll
  for (int j = 0; j < 4; ++j) {
    const int n = n0 + 16 * j + c;
    const float gv = g2[n], bev = be2[n];
#pragma unroll
    for (int rg = 0; rg < 2; ++rg)
#pragma unroll
      for (int r = 0; r < 4; ++r)
        out[(size_t)(m0 + 16 * rg + 4 * g + r) * 256 + n]
            = (t1[rg][j][r] - mean[rg][r]) * inv[rg][r] * gv + bev;
  }
}

extern "C" void kernel_launch(void* const* d_in, const int* in_sizes, int n_in,
                              void* d_out, int out_size, void* d_ws, size_t ws_size,
                              hipStream_t stream) {
  const float* qdt   = (const float*)d_in[0];
  const float* boxes = (const float*)d_in[1];
  const int*   mask  = (const int*)d_in[2];
  const float* Wq = (const float*)d_in[3];
  const float* bq = (const float*)d_in[4];
  const float* Wk = (const float*)d_in[5];
  const float* bk = (const float*)d_in[6];
  const float* Wv = (const float*)d_in[7];
  const float* bv = (const float*)d_in[8];
  const float* Wo = (const float*)d_in[9];
  const float* bo = (const float*)d_in[10];
  const float* W1 = (const float*)d_in[11];
  const float* b1 = (const float*)d_in[12];
  const float* W2 = (const float*)d_in[13];
  const float* b2 = (const float*)d_in[14];
  const float* g1  = (const float*)d_in[15];
  const float* be1 = (const float*)d_in[16];
  const float* g2  = (const float*)d_in[17];
  const float* be2 = (const float*)d_in[18];

  char* ws = (char*)d_ws;
  float* xp    = (float*)(ws + 0);          // [8192,256] f32 permuted residual
  u16*   xb    = (u16*)  (ws + 8388608);
  u16*   qbuf  = (u16*)  (ws + 12582912);   // q, LAMBDA-scaled
  u16*   kbuf  = (u16*)  (ws + 16777216);   // [B][H][2048][32]
  u16*   vtbuf = (u16*)  (ws + 20971520);   // [256][8192]
  u16*   obuf  = (u16*)  (ws + 25165824);
  u16*   wqkvT = (u16*)  (ws + 46137344);   // [768,256]
  u16*   woT   = (u16*)  (ws + 46530560);
  u16*   w1T   = (u16*)  (ws + 46661632);
  u16*   w2T   = (u16*)  (ws + 46792704);
  float* bqkv  = (float*)(ws + 46923776);
  u32*   m1    = (u32*)  (ws + 46926848);   // [2048][64] u32 mask bits (512 KB)

  // merged prep: xp/xb (2048) + mask-bits (512) + weights (1539) = 4099 blocks
  prep_kernel<<<4099, 256, 0, stream>>>(qdt, boxes, mask, Wq, Wk, Wv, Wo, W1, W2,
                                        bq, bk, bv, xp, xb, m1,
                                        wqkvT, woT, w1T, w2T, bqkv);
  // fused Q(scaled)/K(relayout) + V^T: 1024 + 512 blocks
  gemm_qkvt_kernel<<<1536, 256, 0, stream>>>(xb, wqkvT, bqkv, qbuf, kbuf, vtbuf);
  // attention: 1024 blocks x (b,h,64q), 16 waves/CU
  attn_kernel<<<1024, 256, 0, stream>>>(qbuf, kbuf, vtbuf, m1, obuf);
  // fused tail: Wo+res -> LN1 -> FF1+relu -> FF2+res -> LN2 -> d_out
  tail_kernel<<<256, 256, 0, stream>>>(obuf, woT, w1T, w2T, xp,
                                       bo, b1, b2, g1, be1, g2, be2, (float*)d_out);
}

// Round 18
// 109.953 us; speedup vs baseline: 1.1843x; 1.0092x over previous
//
#include <hip/hip_runtime.h>
#include <hip/hip_bf16.h>

typedef unsigned short u16;
typedef unsigned int u32;
typedef __attribute__((ext_vector_type(8))) short bf16x8;   // 8 bf16 (MFMA x32 A/B frag)
typedef __attribute__((ext_vector_type(4))) float f32x4;    // MFMA C/D frag

#define BB 4
#define NN 2048
#define DD 256
#define HH 8
#define LAMBDA (-0.2550351f)  // -log2(e)/sqrt(32): folded into Q so sigmoid = rcp(1+exp2(s))

__device__ inline u16 bfu(float f) {
  __hip_bfloat16 h = __float2bfloat16(f);
  return *reinterpret_cast<u16*>(&h);
}
__device__ inline bf16x8 asfrag(uint4 v) { return __builtin_bit_cast(bf16x8, v); }

// ---------------- merged prep: x(permuted via LDS)+xb, mask->BITS, weights ----------------
__global__ __launch_bounds__(256) void prep_kernel(
    const float* __restrict__ qdt, const float* __restrict__ boxes,
    const int* __restrict__ mask,
    const float* __restrict__ Wq, const float* __restrict__ Wk, const float* __restrict__ Wv,
    const float* __restrict__ Wo, const float* __restrict__ W1, const float* __restrict__ W2,
    const float* __restrict__ bq, const float* __restrict__ bk, const float* __restrict__ bv,
    float* __restrict__ xp, u16* __restrict__ xb, u32* __restrict__ m1,
    u16* __restrict__ wqkvT, u16* __restrict__ woT, u16* __restrict__ w1T, u16* __restrict__ w2T,
    float* __restrict__ bqkv) {
  __shared__ float xs[1024];              // 4 rows x 256 cols (x permutation staging)
  const int bid = blockIdx.x, t = threadIdx.x;
  if (bid < 2048) {                       // x = qdt + boxes; xb linear bf16; xp permuted f32
    int i = bid * 256 + t;                // global float4 index; block = 4 rows
    float4 a = ((const float4*)qdt)[i];
    float4 b = ((const float4*)boxes)[i];
    float4 v = make_float4(a.x + b.x, a.y + b.y, a.z + b.z, a.w + b.w);
    ((ushort4*)xb)[i] = make_ushort4(bfu(v.x), bfu(v.y), bfu(v.z), bfu(v.w));
    ((float4*)xs)[t] = v;                 // xs[r*256 + 4*q + e], r=t>>6, q=t&63
    __syncthreads();
    // coalesced permuted write: xp[row][o]=x[row][16*(o&15)+(o>>4)], o=4q..4q+3
    const int r = t >> 6, q = t & 63;
    const float* xrow = xs + r * 256 + (q >> 2);      // + c
    float o0 = xrow[16 * (4 * (q & 3) + 0)];
    float o1 = xrow[16 * (4 * (q & 3) + 1)];
    float o2 = xrow[16 * (4 * (q & 3) + 2)];
    float o3 = xrow[16 * (4 * (q & 3) + 3)];
    ((float4*)(xp + (size_t)(bid * 4 + r) * 256))[q] = make_float4(o0, o1, o2, o3);
  } else if (bid < 2560) {                // mask: 32 ints -> 1 u32 of bits
    int i = (bid - 2048) * 256 + t;       // i in [0, 131072): m1[row][word]
    const int* src = mask + (size_t)i * 32;
    u32 bits = 0;
#pragma unroll
    for (int q4 = 0; q4 < 8; ++q4) {
      int4 m = *(const int4*)(src + q4 * 4);
      bits |= (m.x ? 1u : 0u) << (4 * q4);
      bits |= (m.y ? 1u : 0u) << (4 * q4 + 1);
      bits |= (m.z ? 1u : 0u) << (4 * q4 + 2);
      bits |= (m.w ? 1u : 0u) << (4 * q4 + 3);
    }
    m1[i] = bits;
  } else {                                // weight transposes + qkv bias concat
    int i = (bid - 2560) * 256 + t;
    if (i < 196608) {
      int n = i >> 8, k = i & 255;
      const float* src = (n < 256) ? Wq : (n < 512 ? Wk : Wv);
      wqkvT[i] = bfu(src[k * 256 + (n & 255)]);
    } else if (i < 262144) {
      int j = i - 196608; int n = j >> 8, k = j & 255;
      woT[j] = bfu(Wo[k * 256 + n]);
    } else if (i < 327680) {
      int j = i - 262144; int n = j >> 8, k = j & 255;
      w1T[j] = bfu(W1[k * 256 + n]);
    } else if (i < 393216) {
      int j = i - 327680; int n = j >> 8, k = j & 255;
      w2T[j] = bfu(W2[k * 256 + n]);
    } else if (i < 393984) {
      int n = i - 393216;
      bqkv[n] = (n < 256) ? bq[n] : (n < 512 ? bk[n - 256] : bv[n - 512]);
    }
  }
}

// ---------------- fused QKV-side GEMM: Q(scaled)+K(relayout) and V^T in one launch -------
__global__ __launch_bounds__(256) void gemm_qkvt_kernel(
    const u16* __restrict__ xb, const u16* __restrict__ wqkvT,
    const float* __restrict__ bqkv,
    u16* __restrict__ qout, u16* __restrict__ kout, u16* __restrict__ vtout) {
  __shared__ u16 At[64][264];
  __shared__ u16 Bs[64][264];
  const int bid = blockIdx.x;
  const bool isqk = bid < 1024;
  const u16* A  = isqk ? xb : (wqkvT + 512 * 256);
  const u16* Bt = isqk ? wqkvT : xb;
  const int m0 = isqk ? (bid >> 3) * 64 : ((bid - 1024) >> 7) * 64;
  const int n0 = isqk ? (bid & 7) * 64 : ((bid - 1024) & 127) * 64;
  const int t = threadIdx.x;
  {
    const int row = t >> 2, cb = (t & 3) * 64;
    const u16* ga = A  + (size_t)(m0 + row) * 256 + cb;
    const u16* gb = Bt + (size_t)(n0 + row) * 256 + cb;
#pragma unroll
    for (int i = 0; i < 8; ++i) {
      *(int4*)&At[row][cb + i * 8] = *(const int4*)(ga + i * 8);
      *(int4*)&Bs[row][cb + i * 8] = *(const int4*)(gb + i * 8);
    }
  }
  __syncthreads();
  const int w = t >> 6, l = t & 63, g = l >> 4, c = l & 15;
  f32x4 acc[4] = {};
#pragma unroll
  for (int kk = 0; kk < 256; kk += 32) {
    bf16x8 af = *(const bf16x8*)&At[w * 16 + c][kk + g * 8];
#pragma unroll
    for (int j = 0; j < 4; ++j) {
      bf16x8 bfr = *(const bf16x8*)&Bs[j * 16 + c][kk + g * 8];
      acc[j] = __builtin_amdgcn_mfma_f32_16x16x32_bf16(af, bfr, acc[j], 0, 0, 0);
    }
  }
  if (isqk) {
    if (n0 < 256) {
#pragma unroll
      for (int j = 0; j < 4; ++j)
#pragma unroll
        for (int r = 0; r < 4; ++r) {
          int m = m0 + w * 16 + g * 4 + r, n = n0 + j * 16 + c;
          qout[(size_t)m * 256 + n] = bfu((acc[j][r] + bqkv[n]) * LAMBDA);
        }
    } else {
#pragma unroll
      for (int j = 0; j < 4; ++j)
#pragma unroll
        for (int r = 0; r < 4; ++r) {
          int m = m0 + w * 16 + g * 4 + r, n = n0 + j * 16 + c;
          int ch = n - 256;
          kout[(size_t)((m >> 11) * 8 + (ch >> 5)) * 65536 + (size_t)(m & 2047) * 32 + (ch & 31)]
              = bfu(acc[j][r] + bqkv[n]);
        }
    }
  } else {
#pragma unroll
    for (int j = 0; j < 4; ++j)
#pragma unroll
      for (int r = 0; r < 4; ++r) {
        int m = m0 + w * 16 + g * 4 + r;   // channel
        int n = n0 + j * 16 + c;           // token
        vtout[(size_t)m * 8192 + n] = bfu(acc[j][r] + bqkv[512 + m]);
      }
  }
}

// ---------------- fused sigmoid-gated attention (r16 PASSING + T5 setprio + XCD swizzle) --
// XCD swizzle: lbid = ((bid&7)<<7)|(bid>>3) is bijective on 1024 and puts all 32
// q-tile blocks sharing one (b,h)'s K/V (640 KB) on the same XCD L2.
// setprio(1) wraps the MFMA+sigmoid compute; staging/barriers stay prio 0 (T5).
__global__ __launch_bounds__(256) void attn_kernel(
    const u16* __restrict__ qb,            // [8192][256] bf16, LAMBDA-scaled
    const u16* __restrict__ kb,            // [B][H][2048][32] bf16
    const u16* __restrict__ vtb,           // [256][8192] bf16 (V^T)
    const u32* __restrict__ m1,            // [2048][64] u32 mask bits
    u16* __restrict__ ob) {                // [8192][256] bf16
  __shared__ u32 Klds[2][64][20];          // 16 data u32 + 4 pad (row 80 B)
  __shared__ u32 Vlds[2][32][36];          // 32 data u32 + 4 pad (row 144 B)
  __shared__ u32 Plds[4][16][36];          // 32 data u32 + 4 pad, per-wave

  const int bid0 = blockIdx.x;
  const int bid = ((bid0 & 7) << 7) | (bid0 >> 3);   // XCD-locality remap (bijective)
  const int qt = bid & 31, h = (bid >> 5) & 7, b = bid >> 8;
  const int q0 = qt * 64;
  const int t = threadIdx.x, w = t >> 6, l = t & 63, g = l >> 4, c = l & 15;

  const bf16x8 qf = asfrag(*(const uint4*)(qb + (size_t)(b * NN + q0 + 16 * w + c) * 256 + h * 32 + 8 * g));
  f32x4 oacc[2] = {};

  const int srowK = t >> 2, ssegK = t & 3;
  const int srowV = t >> 3, ssegV = t & 7;
  const u16* kg = kb + (size_t)(b * 8 + h) * 65536 + srowK * 32 + ssegK * 8;
  const u16* vg = vtb + (size_t)(h * 32 + srowV) * 8192 + (size_t)b * NN + ssegV * 8;
  const u32* mr = m1 + (size_t)(q0 + 16 * w + c) * 64;   // lane's q-row bit words

  uint4 krg = *(const uint4*)kg;
  uint4 vrg = *(const uint4*)vg;
  uint2 mc = *(const uint2*)mr;            // tile-0 64-bit mask for this q-row
  *(uint4*)&Klds[0][srowK][ssegK * 4] = krg;
  *(uint4*)&Vlds[0][srowV][ssegV * 4] = vrg;
  __syncthreads();

  const f32x4 zf = {0.f, 0.f, 0.f, 0.f};
  u32* Pw = &Plds[w][0][0];

  for (int it = 0; it < 32; ++it) {
    const int cur = it & 1;
    uint2 mn;
    if (it < 31) {                         // prefetch tile it+1 (K, V, mask bits)
      const int kt = (it + 1) * 64;
      krg = *(const uint4*)(kg + (size_t)kt * 32);
      vrg = *(const uint4*)(vg + kt);
      mn = *(const uint2*)(mr + (it + 1) * 2);
    }
    __builtin_amdgcn_s_setprio(1);         // T5: favor compute over staging waves
#pragma unroll
    for (int tt = 0; tt < 4; ++tt) {
      bf16x8 kf = asfrag(*(const uint4*)&Klds[cur][16 * tt + c][4 * g]);
      f32x4 s = __builtin_amdgcn_mfma_f32_16x16x32_bf16(kf, qf, zf, 0, 0, 0);
      const u32 wd = (tt < 2) ? mc.x : mc.y;   // word sel compile-time per tt
      const int off = 16 * (tt & 1) + 4 * g;   // bit offset of elem r=0
      float p0 = (float)((wd >> (off + 0)) & 1u) * __builtin_amdgcn_rcpf(1.f + __builtin_amdgcn_exp2f(s[0]));
      float p1 = (float)((wd >> (off + 1)) & 1u) * __builtin_amdgcn_rcpf(1.f + __builtin_amdgcn_exp2f(s[1]));
      float p2 = (float)((wd >> (off + 2)) & 1u) * __builtin_amdgcn_rcpf(1.f + __builtin_amdgcn_exp2f(s[2]));
      float p3 = (float)((wd >> (off + 3)) & 1u) * __builtin_amdgcn_rcpf(1.f + __builtin_amdgcn_exp2f(s[3]));
      u32 w0, w1;
      asm("v_cvt_pk_bf16_f32 %0, %1, %2" : "=v"(w0) : "v"(p0), "v"(p1));
      asm("v_cvt_pk_bf16_f32 %0, %1, %2" : "=v"(w1) : "v"(p2), "v"(p3));
      *(uint2*)&Pw[c * 36 + 8 * tt + 2 * g] = make_uint2(w0, w1);
    }
    __builtin_amdgcn_s_setprio(0);
    // RULE-18 hard fence on wave-private P
    asm volatile("s_waitcnt lgkmcnt(0)" ::: "memory");
    __builtin_amdgcn_sched_barrier(0);
    __builtin_amdgcn_s_setprio(1);
#pragma unroll
    for (int kk = 0; kk < 2; ++kk) {
      bf16x8 pf = asfrag(*(const uint4*)&Pw[c * 36 + 16 * kk + 4 * g]);
#pragma unroll
      for (int d0 = 0; d0 < 2; ++d0) {
        bf16x8 vf = asfrag(*(const uint4*)&Vlds[cur][16 * d0 + c][16 * kk + 4 * g]);
        oacc[d0] = __builtin_amdgcn_mfma_f32_16x16x32_bf16(pf, vf, oacc[d0], 0, 0, 0);
      }
    }
    __builtin_amdgcn_s_setprio(0);
    if (it < 31) {
      *(uint4*)&Klds[cur ^ 1][srowK][ssegK * 4] = krg;
      *(uint4*)&Vlds[cur ^ 1][srowV][ssegV * 4] = vrg;
      mc = mn;
    }
    __syncthreads();
  }

  const size_t obase = (size_t)(b * NN + q0 + 16 * w) * 256 + h * 32;
#pragma unroll
  for (int d0 = 0; d0 < 2; ++d0)
#pragma unroll
    for (int r = 0; r < 4; ++r)
      ob[obase + (size_t)(4 * g + r) * 256 + 16 * d0 + c] = bfu(oacc[d0][r]);
}

// ---------------- fused tail v3: Wo+res -> LN1 -> FF1+relu -> FF2+res -> LN2 -------------
// (unchanged from round-12 PASSING build)
__global__ __launch_bounds__(256) void tail_kernel(
    const u16* __restrict__ obuf, const u16* __restrict__ woT,
    const u16* __restrict__ w1T, const u16* __restrict__ w2T,
    const float* __restrict__ xp,          // [8192][256] f32, permuted [row][c*16+4w+j]
    const float* __restrict__ bo, const float* __restrict__ b1, const float* __restrict__ b2,
    const float* __restrict__ g1, const float* __restrict__ be1,
    const float* __restrict__ g2, const float* __restrict__ be2,
    float* __restrict__ out) {
  __shared__ u16 A[32][264];               // bf16 activation tile
  __shared__ float PS1[32][4], PS2[32][4]; // cross-wave LN partials
  const int t = threadIdx.x, w = t >> 6, l = t & 63, g = l >> 4, c = l & 15;
  const int m0 = blockIdx.x * 32;          // block's 32 rows
  const int n0 = w * 64;                   // wave's 64 cols
  const f32x4 zf4 = {0.f, 0.f, 0.f, 0.f};

  // ---- stage obuf rows m0..m0+31 (256 threads, 4 x 16B each) ----
  {
    const int srow = t >> 3, sseg = t & 7;
#pragma unroll
    for (int i = 0; i < 4; ++i) {
      uint4 v = *(const uint4*)(obuf + (size_t)(m0 + srow) * 256 + (sseg + 8 * i) * 8);
      *(uint4*)&A[srow][(sseg + 8 * i) * 8] = v;
    }
  }
  __syncthreads();

  f32x4 acc[2][4], t1[2][4];
  float mean[2][4], inv[2][4];

  // ---- GEMM1: obuf @ Wo ----
#pragma unroll
  for (int rg = 0; rg < 2; ++rg)
#pragma unroll
    for (int j = 0; j < 4; ++j) acc[rg][j] = zf4;
#pragma unroll
  for (int kk = 0; kk < 256; kk += 32) {
    bf16x8 af0 = *(const bf16x8*)&A[c][kk + 8 * g];
    bf16x8 af1 = *(const bf16x8*)&A[16 + c][kk + 8 * g];
#pragma unroll
    for (int j = 0; j < 4; ++j) {
      bf16x8 bfr = asfrag(*(const uint4*)(woT + (size_t)(n0 + 16 * j + c) * 256 + kk + 8 * g));
      acc[0][j] = __builtin_amdgcn_mfma_f32_16x16x32_bf16(af0, bfr, acc[0][j], 0, 0, 0);
      acc[1][j] = __builtin_amdgcn_mfma_f32_16x16x32_bf16(af1, bfr, acc[1][j], 0, 0, 0);
    }
  }
  // ---- epilogue1: z = acc + bo + x -> t1 regs; LN1 partials -> PS ----
  {
    float bov[4];
#pragma unroll
    for (int j = 0; j < 4; ++j) bov[j] = bo[n0 + 16 * j + c];
#pragma unroll
    for (int rg = 0; rg < 2; ++rg)
#pragma unroll
      for (int r = 0; r < 4; ++r) {
        const int rl = 16 * rg + 4 * g + r;
        float4 xq = ((const float4*)(xp + (size_t)(m0 + rl) * 256 + c * 16))[w];
        float xa[4] = {xq.x, xq.y, xq.z, xq.w};
        float a1 = 0.f, a2 = 0.f;
#pragma unroll
        for (int j = 0; j < 4; ++j) {
          float z = acc[rg][j][r] + bov[j] + xa[j];
          t1[rg][j][r] = z;
          a1 += z; a2 += z * z;
        }
#pragma unroll
        for (int off = 1; off < 16; off <<= 1) {
          a1 += __shfl_xor(a1, off);
          a2 += __shfl_xor(a2, off);
        }
        if (c == 0) { PS1[rl][w] = a1; PS2[rl][w] = a2; }
      }
  }
  __syncthreads();
#pragma unroll
  for (int rg = 0; rg < 2; ++rg)
#pragma unroll
    for (int r = 0; r < 4; ++r) {
      const int rl = 16 * rg + 4 * g + r;
      float s1 = PS1[rl][0] + PS1[rl][1] + PS1[rl][2] + PS1[rl][3];
      float s2 = PS2[rl][0] + PS2[rl][1] + PS2[rl][2] + PS2[rl][3];
      mean[rg][r] = s1 * (1.f / 256.f);
      inv[rg][r] = rsqrtf(s2 * (1.f / 256.f) - mean[rg][r] * mean[rg][r] + 1e-5f);
    }
  // normalize into t1 regs (kept for FF2 residual) + bf16 tile -> A
#pragma unroll
  for (int j = 0; j < 4; ++j) {
    const int n = n0 + 16 * j + c;
    const float gv = g1[n], bev = be1[n];
#pragma unroll
    for (int rg = 0; rg < 2; ++rg)
#pragma unroll
      for (int r = 0; r < 4; ++r) {
        float v = (t1[rg][j][r] - mean[rg][r]) * inv[rg][r] * gv + bev;
        t1[rg][j][r] = v;
        A[16 * rg + 4 * g + r][n] = bfu(v);
      }
  }
  __syncthreads();

  // ---- GEMM2: t1 @ W1, relu ----
#pragma unroll
  for (int rg = 0; rg < 2; ++rg)
#pragma unroll
    for (int j = 0; j < 4; ++j) acc[rg][j] = zf4;
#pragma unroll
  for (int kk = 0; kk < 256; kk += 32) {
    bf16x8 af0 = *(const bf16x8*)&A[c][kk + 8 * g];
    bf16x8 af1 = *(const bf16x8*)&A[16 + c][kk + 8 * g];
#pragma unroll
    for (int j = 0; j < 4; ++j) {
      bf16x8 bfr = asfrag(*(const uint4*)(w1T + (size_t)(n0 + 16 * j + c) * 256 + kk + 8 * g));
      acc[0][j] = __builtin_amdgcn_mfma_f32_16x16x32_bf16(af0, bfr, acc[0][j], 0, 0, 0);
      acc[1][j] = __builtin_amdgcn_mfma_f32_16x16x32_bf16(af1, bfr, acc[1][j], 0, 0, 0);
    }
  }
  __syncthreads();                         // all waves done reading A
#pragma unroll
  for (int j = 0; j < 4; ++j) {
    const int n = n0 + 16 * j + c;
    const float bv = b1[n];
#pragma unroll
    for (int rg = 0; rg < 2; ++rg)
#pragma unroll
      for (int r = 0; r < 4; ++r) {
        float v = acc[rg][j][r] + bv;
        A[16 * rg + 4 * g + r][n] = bfu(v > 0.f ? v : 0.f);
      }
  }
  __syncthreads();

  // ---- GEMM3: h @ W2 ----
#pragma unroll
  for (int rg = 0; rg < 2; ++rg)
#pragma unroll
    for (int j = 0; j < 4; ++j) acc[rg][j] = zf4;
#pragma unroll
  for (int kk = 0; kk < 256; kk += 32) {
    bf16x8 af0 = *(const bf16x8*)&A[c][kk + 8 * g];
    bf16x8 af1 = *(const bf16x8*)&A[16 + c][kk + 8 * g];
#pragma unroll
    for (int j = 0; j < 4; ++j) {
      bf16x8 bfr = asfrag(*(const uint4*)(w2T + (size_t)(n0 + 16 * j + c) * 256 + kk + 8 * g));
      acc[0][j] = __builtin_amdgcn_mfma_f32_16x16x32_bf16(af0, bfr, acc[0][j], 0, 0, 0);
      acc[1][j] = __builtin_amdgcn_mfma_f32_16x16x32_bf16(af1, bfr, acc[1][j], 0, 0, 0);
    }
  }
  // ---- epilogue3: z = acc + b2 + t1 (regs); LN2 -> out ----
  {
    float b2v[4];
#pragma unroll
    for (int j = 0; j < 4; ++j) b2v[j] = b2[n0 + 16 * j + c];
#pragma unroll
    for (int rg = 0; rg < 2; ++rg)
#pragma unroll
      for (int r = 0; r < 4; ++r) {
        const int rl = 16 * rg + 4 * g + r;
        float a1 = 0.f, a2 = 0.f;
#pragma unroll
        for (int j = 0; j < 4; ++j) {
          float z = acc[rg][j][r] + b2v[j] + t1[rg][j][r];
          t1[rg][j][r] = z;
          a1 += z; a2 += z * z;
        }
#pragma unroll
        for (int off = 1; off < 16; off <<= 1) {
          a1 += __shfl_xor(a1, off);
          a2 += __shfl_xor(a2, off);
        }
        if (c == 0) { PS1[rl][w] = a1; PS2[rl][w] = a2; }
      }
  }
  __syncthreads();
#pragma unroll
  for (int rg = 0; rg < 2; ++rg)
#pragma unroll
    for (int r = 0; r < 4; ++r) {
      const int rl = 16 * rg + 4 * g + r;
      float s1 = PS1[rl][0] + PS1[rl][1] + PS1[rl][2] + PS1[rl][3];
      float s2 = PS2[rl][0] + PS2[rl][1] + PS2[rl][2] + PS2[rl][3];
      mean[rg][r] = s1 * (1.f / 256.f);
      inv[rg][r] = rsqrtf(s2 * (1.f / 256.f) - mean[rg][r] * mean[rg][r] + 1e-5f);
    }
#pragma unroll
  for (int j = 0; j < 4; ++j) {
    const int n = n0 + 16 * j + c;
    const float gv = g2[n], bev = be2[n];
#pragma unroll
    for (int rg = 0; rg < 2; ++rg)
#pragma unroll
      for (int r = 0; r < 4; ++r)
        out[(size_t)(m0 + 16 * rg + 4 * g + r) * 256 + n]
            = (t1[rg][j][r] - mean[rg][r]) * inv[rg][r] * gv + bev;
  }
}

extern "C" void kernel_launch(void* const* d_in, const int* in_sizes, int n_in,
                              void* d_out, int out_size, void* d_ws, size_t ws_size,
                              hipStream_t stream) {
  const float* qdt   = (const float*)d_in[0];
  const float* boxes = (const float*)d_in[1];
  const int*   mask  = (const int*)d_in[2];
  const float* Wq = (const float*)d_in[3];
  const float* bq = (const float*)d_in[4];
  const float* Wk = (const float*)d_in[5];
  const float* bk = (const float*)d_in[6];
  const float* Wv = (const float*)d_in[7];
  const float* bv = (const float*)d_in[8];
  const float* Wo = (const float*)d_in[9];
  const float* bo = (const float*)d_in[10];
  const float* W1 = (const float*)d_in[11];
  const float* b1 = (const float*)d_in[12];
  const float* W2 = (const float*)d_in[13];
  const float* b2 = (const float*)d_in[14];
  const float* g1  = (const float*)d_in[15];
  const float* be1 = (const float*)d_in[16];
  const float* g2  = (const float*)d_in[17];
  const float* be2 = (const float*)d_in[18];

  char* ws = (char*)d_ws;
  float* xp    = (float*)(ws + 0);          // [8192,256] f32 permuted residual
  u16*   xb    = (u16*)  (ws + 8388608);
  u16*   qbuf  = (u16*)  (ws + 12582912);   // q, LAMBDA-scaled
  u16*   kbuf  = (u16*)  (ws + 16777216);   // [B][H][2048][32]
  u16*   vtbuf = (u16*)  (ws + 20971520);   // [256][8192]
  u16*   obuf  = (u16*)  (ws + 25165824);
  u16*   wqkvT = (u16*)  (ws + 46137344);   // [768,256]
  u16*   woT   = (u16*)  (ws + 46530560);
  u16*   w1T   = (u16*)  (ws + 46661632);
  u16*   w2T   = (u16*)  (ws + 46792704);
  float* bqkv  = (float*)(ws + 46923776);
  u32*   m1    = (u32*)  (ws + 46926848);   // [2048][64] u32 mask bits (512 KB)

  // merged prep: xp/xb (2048) + mask-bits (512) + weights (1539) = 4099 blocks
  prep_kernel<<<4099, 256, 0, stream>>>(qdt, boxes, mask, Wq, Wk, Wv, Wo, W1, W2,
                                        bq, bk, bv, xp, xb, m1,
                                        wqkvT, woT, w1T, w2T, bqkv);
  // fused Q(scaled)/K(relayout) + V^T: 1024 + 512 blocks
  gemm_qkvt_kernel<<<1536, 256, 0, stream>>>(xb, wqkvT, bqkv, qbuf, kbuf, vtbuf);
  // attention: 1024 blocks x (b,h,64q), XCD-swizzled
  attn_kernel<<<1024, 256, 0, stream>>>(qbuf, kbuf, vtbuf, m1, obuf);
  // fused tail: Wo+res -> LN1 -> FF1+relu -> FF2+res -> LN2 -> d_out
  tail_kernel<<<256, 256, 0, stream>>>(obuf, woT, w1T, w2T, xp,
                                       bo, b1, b2, g1, be1, g2, be2, (float*)d_out);
}

// Round 19
// 108.978 us; speedup vs baseline: 1.1949x; 1.0089x over previous
//
#include <hip/hip_runtime.h>
#include <hip/hip_bf16.h>

typedef unsigned short u16;
typedef unsigned int u32;
typedef __attribute__((ext_vector_type(8))) short bf16x8;   // 8 bf16 (MFMA x32 A/B frag)
typedef __attribute__((ext_vector_type(4))) float f32x4;    // MFMA C/D frag

#define BB 4
#define NN 2048
#define DD 256
#define HH 8
#define LAMBDA (-0.2550351f)  // -log2(e)/sqrt(32): folded into Q so sigmoid = rcp(1+exp2(s))

__device__ inline u16 bfu(float f) {
  __hip_bfloat16 h = __float2bfloat16(f);
  return *reinterpret_cast<u16*>(&h);
}
__device__ inline bf16x8 asfrag(uint4 v) { return __builtin_bit_cast(bf16x8, v); }

// ---------------- merged prep: x(permuted via LDS)+xb, mask->BITS, weights(LDS transpose) --
__global__ __launch_bounds__(256) void prep_kernel(
    const float* __restrict__ qdt, const float* __restrict__ boxes,
    const int* __restrict__ mask,
    const float* __restrict__ Wq, const float* __restrict__ Wk, const float* __restrict__ Wv,
    const float* __restrict__ Wo, const float* __restrict__ W1, const float* __restrict__ W2,
    const float* __restrict__ bq, const float* __restrict__ bk, const float* __restrict__ bv,
    float* __restrict__ xp, u16* __restrict__ xb, u32* __restrict__ m1,
    u16* __restrict__ wqkvT, u16* __restrict__ woT, u16* __restrict__ w1T, u16* __restrict__ w2T,
    float* __restrict__ bqkv) {
  __shared__ float xs[4160];              // x-perm staging (1024) / weight tile [64][65]
  const int bid = blockIdx.x, t = threadIdx.x;
  if (bid < 2048) {                       // x = qdt + boxes; xb linear bf16; xp permuted f32
    int i = bid * 256 + t;                // global float4 index; block = 4 rows
    float4 a = ((const float4*)qdt)[i];
    float4 b = ((const float4*)boxes)[i];
    float4 v = make_float4(a.x + b.x, a.y + b.y, a.z + b.z, a.w + b.w);
    ((ushort4*)xb)[i] = make_ushort4(bfu(v.x), bfu(v.y), bfu(v.z), bfu(v.w));
    ((float4*)xs)[t] = v;                 // xs[r*256 + 4*q + e], r=t>>6, q=t&63
    __syncthreads();
    // coalesced permuted write: xp[row][o]=x[row][16*(o&15)+(o>>4)], o=4q..4q+3
    const int r = t >> 6, q = t & 63;
    const float* xrow = xs + r * 256 + (q >> 2);      // + c
    float o0 = xrow[16 * (4 * (q & 3) + 0)];
    float o1 = xrow[16 * (4 * (q & 3) + 1)];
    float o2 = xrow[16 * (4 * (q & 3) + 2)];
    float o3 = xrow[16 * (4 * (q & 3) + 3)];
    ((float4*)(xp + (size_t)(bid * 4 + r) * 256))[q] = make_float4(o0, o1, o2, o3);
  } else if (bid < 2560) {                // mask: 32 ints -> 1 u32 of bits
    int i = (bid - 2048) * 256 + t;       // i in [0, 131072): m1[row][word]
    const int* src = mask + (size_t)i * 32;
    u32 bits = 0;
#pragma unroll
    for (int q4 = 0; q4 < 8; ++q4) {
      int4 m = *(const int4*)(src + q4 * 4);
      bits |= (m.x ? 1u : 0u) << (4 * q4);
      bits |= (m.y ? 1u : 0u) << (4 * q4 + 1);
      bits |= (m.z ? 1u : 0u) << (4 * q4 + 2);
      bits |= (m.w ? 1u : 0u) << (4 * q4 + 3);
    }
    m1[i] = bits;
  } else if (bid < 2656) {                // weight transpose via LDS: 96 blocks (6 mats x 16 tiles)
    const int b = bid - 2560;             // 0..95
    const int mtx = b >> 4, tile = b & 15;
    const int kt = (tile >> 2) * 64, nt = (tile & 3) * 64;
    const float* src = (mtx == 0) ? Wq : (mtx == 1) ? Wk : (mtx == 2) ? Wv
                     : (mtx == 3) ? Wo : (mtx == 4) ? W1 : W2;
    u16* dst = (mtx < 3) ? (wqkvT + mtx * 65536) : (mtx == 3) ? woT : (mtx == 4) ? w1T : w2T;
    const int r = t >> 2, q = t & 3;      // r: tile row 0..63, q: col quarter
    // load [64 k][64 n] fp32 tile, coalesced float4
#pragma unroll
    for (int j = 0; j < 4; ++j) {
      float4 v = *(const float4*)(src + (size_t)(kt + r) * 256 + nt + 16 * q + 4 * j);
      float* xr = xs + r * 65 + 16 * q + 4 * j;
      xr[0] = v.x; xr[1] = v.y; xr[2] = v.z; xr[3] = v.w;
    }
    __syncthreads();
    // transposed write: dst[nt+nn][kt + cc] = tile[cc][nn], packed ushort4
    const int nn = r;
#pragma unroll
    for (int j = 0; j < 4; ++j) {
      ushort4 o;
      o.x = bfu(xs[(16 * q + 4 * j + 0) * 65 + nn]);
      o.y = bfu(xs[(16 * q + 4 * j + 1) * 65 + nn]);
      o.z = bfu(xs[(16 * q + 4 * j + 2) * 65 + nn]);
      o.w = bfu(xs[(16 * q + 4 * j + 3) * 65 + nn]);
      *(ushort4*)(dst + (size_t)(nt + nn) * 256 + kt + 16 * q + 4 * j) = o;
    }
  } else {                                // bias concat (1 block)
    if (t < 256) {
      bqkv[t] = bq[t];
      bqkv[256 + t] = bk[t];
      bqkv[512 + t] = bv[t];
    }
  }
}

// ---------------- fused QKV-side GEMM: Q(scaled)+K(relayout) and V^T in one launch -------
__global__ __launch_bounds__(256) void gemm_qkvt_kernel(
    const u16* __restrict__ xb, const u16* __restrict__ wqkvT,
    const float* __restrict__ bqkv,
    u16* __restrict__ qout, u16* __restrict__ kout, u16* __restrict__ vtout) {
  __shared__ u16 At[64][264];
  __shared__ u16 Bs[64][264];
  const int bid = blockIdx.x;
  const bool isqk = bid < 1024;
  const u16* A  = isqk ? xb : (wqkvT + 512 * 256);
  const u16* Bt = isqk ? wqkvT : xb;
  const int m0 = isqk ? (bid >> 3) * 64 : ((bid - 1024) >> 7) * 64;
  const int n0 = isqk ? (bid & 7) * 64 : ((bid - 1024) & 127) * 64;
  const int t = threadIdx.x;
  {
    const int row = t >> 2, cb = (t & 3) * 64;
    const u16* ga = A  + (size_t)(m0 + row) * 256 + cb;
    const u16* gb = Bt + (size_t)(n0 + row) * 256 + cb;
#pragma unroll
    for (int i = 0; i < 8; ++i) {
      *(int4*)&At[row][cb + i * 8] = *(const int4*)(ga + i * 8);
      *(int4*)&Bs[row][cb + i * 8] = *(const int4*)(gb + i * 8);
    }
  }
  __syncthreads();
  const int w = t >> 6, l = t & 63, g = l >> 4, c = l & 15;
  f32x4 acc[4] = {};
#pragma unroll
  for (int kk = 0; kk < 256; kk += 32) {
    bf16x8 af = *(const bf16x8*)&At[w * 16 + c][kk + g * 8];
#pragma unroll
    for (int j = 0; j < 4; ++j) {
      bf16x8 bfr = *(const bf16x8*)&Bs[j * 16 + c][kk + g * 8];
      acc[j] = __builtin_amdgcn_mfma_f32_16x16x32_bf16(af, bfr, acc[j], 0, 0, 0);
    }
  }
  if (isqk) {
    if (n0 < 256) {
#pragma unroll
      for (int j = 0; j < 4; ++j)
#pragma unroll
        for (int r = 0; r < 4; ++r) {
          int m = m0 + w * 16 + g * 4 + r, n = n0 + j * 16 + c;
          qout[(size_t)m * 256 + n] = bfu((acc[j][r] + bqkv[n]) * LAMBDA);
        }
    } else {
#pragma unroll
      for (int j = 0; j < 4; ++j)
#pragma unroll
        for (int r = 0; r < 4; ++r) {
          int m = m0 + w * 16 + g * 4 + r, n = n0 + j * 16 + c;
          int ch = n - 256;
          kout[(size_t)((m >> 11) * 8 + (ch >> 5)) * 65536 + (size_t)(m & 2047) * 32 + (ch & 31)]
              = bfu(acc[j][r] + bqkv[n]);
        }
    }
  } else {
#pragma unroll
    for (int j = 0; j < 4; ++j)
#pragma unroll
      for (int r = 0; r < 4; ++r) {
        int m = m0 + w * 16 + g * 4 + r;   // channel
        int n = n0 + j * 16 + c;           // token
        vtout[(size_t)m * 8192 + n] = bfu(acc[j][r] + bqkv[512 + m]);
      }
  }
}

// ---------------- fused sigmoid-gated attention (r17 PASSING build, unchanged) ----------
__global__ __launch_bounds__(256) void attn_kernel(
    const u16* __restrict__ qb,            // [8192][256] bf16, LAMBDA-scaled
    const u16* __restrict__ kb,            // [B][H][2048][32] bf16
    const u16* __restrict__ vtb,           // [256][8192] bf16 (V^T)
    const u32* __restrict__ m1,            // [2048][64] u32 mask bits
    u16* __restrict__ ob) {                // [8192][256] bf16
  __shared__ u32 Klds[2][64][20];          // 16 data u32 + 4 pad (row 80 B)
  __shared__ u32 Vlds[2][32][36];          // 32 data u32 + 4 pad (row 144 B)
  __shared__ u32 Plds[4][16][36];          // 32 data u32 + 4 pad, per-wave

  const int bid0 = blockIdx.x;
  const int bid = ((bid0 & 7) << 7) | (bid0 >> 3);   // XCD-locality remap (bijective)
  const int qt = bid & 31, h = (bid >> 5) & 7, b = bid >> 8;
  const int q0 = qt * 64;
  const int t = threadIdx.x, w = t >> 6, l = t & 63, g = l >> 4, c = l & 15;

  const bf16x8 qf = asfrag(*(const uint4*)(qb + (size_t)(b * NN + q0 + 16 * w + c) * 256 + h * 32 + 8 * g));
  f32x4 oacc[2] = {};

  const int srowK = t >> 2, ssegK = t & 3;
  const int srowV = t >> 3, ssegV = t & 7;
  const u16* kg = kb + (size_t)(b * 8 + h) * 65536 + srowK * 32 + ssegK * 8;
  const u16* vg = vtb + (size_t)(h * 32 + srowV) * 8192 + (size_t)b * NN + ssegV * 8;
  const u32* mr = m1 + (size_t)(q0 + 16 * w + c) * 64;   // lane's q-row bit words

  uint4 krg = *(const uint4*)kg;
  uint4 vrg = *(const uint4*)vg;
  uint2 mc = *(const uint2*)mr;            // tile-0 64-bit mask for this q-row
  *(uint4*)&Klds[0][srowK][ssegK * 4] = krg;
  *(uint4*)&Vlds[0][srowV][ssegV * 4] = vrg;
  __syncthreads();

  const f32x4 zf = {0.f, 0.f, 0.f, 0.f};
  u32* Pw = &Plds[w][0][0];

  for (int it = 0; it < 32; ++it) {
    const int cur = it & 1;
    uint2 mn;
    if (it < 31) {                         // prefetch tile it+1 (K, V, mask bits)
      const int kt = (it + 1) * 64;
      krg = *(const uint4*)(kg + (size_t)kt * 32);
      vrg = *(const uint4*)(vg + kt);
      mn = *(const uint2*)(mr + (it + 1) * 2);
    }
    __builtin_amdgcn_s_setprio(1);         // T5: favor compute over staging waves
#pragma unroll
    for (int tt = 0; tt < 4; ++tt) {
      bf16x8 kf = asfrag(*(const uint4*)&Klds[cur][16 * tt + c][4 * g]);
      f32x4 s = __builtin_amdgcn_mfma_f32_16x16x32_bf16(kf, qf, zf, 0, 0, 0);
      const u32 wd = (tt < 2) ? mc.x : mc.y;   // word sel compile-time per tt
      const int off = 16 * (tt & 1) + 4 * g;   // bit offset of elem r=0
      float p0 = (float)((wd >> (off + 0)) & 1u) * __builtin_amdgcn_rcpf(1.f + __builtin_amdgcn_exp2f(s[0]));
      float p1 = (float)((wd >> (off + 1)) & 1u) * __builtin_amdgcn_rcpf(1.f + __builtin_amdgcn_exp2f(s[1]));
      float p2 = (float)((wd >> (off + 2)) & 1u) * __builtin_amdgcn_rcpf(1.f + __builtin_amdgcn_exp2f(s[2]));
      float p3 = (float)((wd >> (off + 3)) & 1u) * __builtin_amdgcn_rcpf(1.f + __builtin_amdgcn_exp2f(s[3]));
      u32 w0, w1;
      asm("v_cvt_pk_bf16_f32 %0, %1, %2" : "=v"(w0) : "v"(p0), "v"(p1));
      asm("v_cvt_pk_bf16_f32 %0, %1, %2" : "=v"(w1) : "v"(p2), "v"(p3));
      *(uint2*)&Pw[c * 36 + 8 * tt + 2 * g] = make_uint2(w0, w1);
    }
    __builtin_amdgcn_s_setprio(0);
    // RULE-18 hard fence on wave-private P
    asm volatile("s_waitcnt lgkmcnt(0)" ::: "memory");
    __builtin_amdgcn_sched_barrier(0);
    __builtin_amdgcn_s_setprio(1);
#pragma unroll
    for (int kk = 0; kk < 2; ++kk) {
      bf16x8 pf = asfrag(*(const uint4*)&Pw[c * 36 + 16 * kk + 4 * g]);
#pragma unroll
      for (int d0 = 0; d0 < 2; ++d0) {
        bf16x8 vf = asfrag(*(const uint4*)&Vlds[cur][16 * d0 + c][16 * kk + 4 * g]);
        oacc[d0] = __builtin_amdgcn_mfma_f32_16x16x32_bf16(pf, vf, oacc[d0], 0, 0, 0);
      }
    }
    __builtin_amdgcn_s_setprio(0);
    if (it < 31) {
      *(uint4*)&Klds[cur ^ 1][srowK][ssegK * 4] = krg;
      *(uint4*)&Vlds[cur ^ 1][srowV][ssegV * 4] = vrg;
      mc = mn;
    }
    __syncthreads();
  }

  const size_t obase = (size_t)(b * NN + q0 + 16 * w) * 256 + h * 32;
#pragma unroll
  for (int d0 = 0; d0 < 2; ++d0)
#pragma unroll
    for (int r = 0; r < 4; ++r)
      ob[obase + (size_t)(4 * g + r) * 256 + 16 * d0 + c] = bfu(oacc[d0][r]);
}

// ---------------- fused tail v3: Wo+res -> LN1 -> FF1+relu -> FF2+res -> LN2 -------------
// (unchanged from round-12 PASSING build)
__global__ __launch_bounds__(256) void tail_kernel(
    const u16* __restrict__ obuf, const u16* __restrict__ woT,
    const u16* __restrict__ w1T, const u16* __restrict__ w2T,
    const float* __restrict__ xp,          // [8192][256] f32, permuted [row][c*16+4w+j]
    const float* __restrict__ bo, const float* __restrict__ b1, const float* __restrict__ b2,
    const float* __restrict__ g1, const float* __restrict__ be1,
    const float* __restrict__ g2, const float* __restrict__ be2,
    float* __restrict__ out) {
  __shared__ u16 A[32][264];               // bf16 activation tile
  __shared__ float PS1[32][4], PS2[32][4]; // cross-wave LN partials
  const int t = threadIdx.x, w = t >> 6, l = t & 63, g = l >> 4, c = l & 15;
  const int m0 = blockIdx.x * 32;          // block's 32 rows
  const int n0 = w * 64;                   // wave's 64 cols
  const f32x4 zf4 = {0.f, 0.f, 0.f, 0.f};

  // ---- stage obuf rows m0..m0+31 (256 threads, 4 x 16B each) ----
  {
    const int srow = t >> 3, sseg = t & 7;
#pragma unroll
    for (int i = 0; i < 4; ++i) {
      uint4 v = *(const uint4*)(obuf + (size_t)(m0 + srow) * 256 + (sseg + 8 * i) * 8);
      *(uint4*)&A[srow][(sseg + 8 * i) * 8] = v;
    }
  }
  __syncthreads();

  f32x4 acc[2][4], t1[2][4];
  float mean[2][4], inv[2][4];

  // ---- GEMM1: obuf @ Wo ----
#pragma unroll
  for (int rg = 0; rg < 2; ++rg)
#pragma unroll
    for (int j = 0; j < 4; ++j) acc[rg][j] = zf4;
#pragma unroll
  for (int kk = 0; kk < 256; kk += 32) {
    bf16x8 af0 = *(const bf16x8*)&A[c][kk + 8 * g];
    bf16x8 af1 = *(const bf16x8*)&A[16 + c][kk + 8 * g];
#pragma unroll
    for (int j = 0; j < 4; ++j) {
      bf16x8 bfr = asfrag(*(const uint4*)(woT + (size_t)(n0 + 16 * j + c) * 256 + kk + 8 * g));
      acc[0][j] = __builtin_amdgcn_mfma_f32_16x16x32_bf16(af0, bfr, acc[0][j], 0, 0, 0);
      acc[1][j] = __builtin_amdgcn_mfma_f32_16x16x32_bf16(af1, bfr, acc[1][j], 0, 0, 0);
    }
  }
  // ---- epilogue1: z = acc + bo + x -> t1 regs; LN1 partials -> PS ----
  {
    float bov[4];
#pragma unroll
    for (int j = 0; j < 4; ++j) bov[j] = bo[n0 + 16 * j + c];
#pragma unroll
    for (int rg = 0; rg < 2; ++rg)
#pragma unroll
      for (int r = 0; r < 4; ++r) {
        const int rl = 16 * rg + 4 * g + r;
        float4 xq = ((const float4*)(xp + (size_t)(m0 + rl) * 256 + c * 16))[w];
        float xa[4] = {xq.x, xq.y, xq.z, xq.w};
        float a1 = 0.f, a2 = 0.f;
#pragma unroll
        for (int j = 0; j < 4; ++j) {
          float z = acc[rg][j][r] + bov[j] + xa[j];
          t1[rg][j][r] = z;
          a1 += z; a2 += z * z;
        }
#pragma unroll
        for (int off = 1; off < 16; off <<= 1) {
          a1 += __shfl_xor(a1, off);
          a2 += __shfl_xor(a2, off);
        }
        if (c == 0) { PS1[rl][w] = a1; PS2[rl][w] = a2; }
      }
  }
  __syncthreads();
#pragma unroll
  for (int rg = 0; rg < 2; ++rg)
#pragma unroll
    for (int r = 0; r < 4; ++r) {
      const int rl = 16 * rg + 4 * g + r;
      float s1 = PS1[rl][0] + PS1[rl][1] + PS1[rl][2] + PS1[rl][3];
      float s2 = PS2[rl][0] + PS2[rl][1] + PS2[rl][2] + PS2[rl][3];
      mean[rg][r] = s1 * (1.f / 256.f);
      inv[rg][r] = rsqrtf(s2 * (1.f / 256.f) - mean[rg][r] * mean[rg][r] + 1e-5f);
    }
  // normalize into t1 regs (kept for FF2 residual) + bf16 tile -> A
#pragma unroll
  for (int j = 0; j < 4; ++j) {
    const int n = n0 + 16 * j + c;
    const float gv = g1[n], bev = be1[n];
#pragma unroll
    for (int rg = 0; rg < 2; ++rg)
#pragma unroll
      for (int r = 0; r < 4; ++r) {
        float v = (t1[rg][j][r] - mean[rg][r]) * inv[rg][r] * gv + bev;
        t1[rg][j][r] = v;
        A[16 * rg + 4 * g + r][n] = bfu(v);
      }
  }
  __syncthreads();

  // ---- GEMM2: t1 @ W1, relu ----
#pragma unroll
  for (int rg = 0; rg < 2; ++rg)
#pragma unroll
    for (int j = 0; j < 4; ++j) acc[rg][j] = zf4;
#pragma unroll
  for (int kk = 0; kk < 256; kk += 32) {
    bf16x8 af0 = *(const bf16x8*)&A[c][kk + 8 * g];
    bf16x8 af1 = *(const bf16x8*)&A[16 + c][kk + 8 * g];
#pragma unroll
    for (int j = 0; j < 4; ++j) {
      bf16x8 bfr = asfrag(*(const uint4*)(w1T + (size_t)(n0 + 16 * j + c) * 256 + kk + 8 * g));
      acc[0][j] = __builtin_amdgcn_mfma_f32_16x16x32_bf16(af0, bfr, acc[0][j], 0, 0, 0);
      acc[1][j] = __builtin_amdgcn_mfma_f32_16x16x32_bf16(af1, bfr, acc[1][j], 0, 0, 0);
    }
  }
  __syncthreads();                         // all waves done reading A
#pragma unroll
  for (int j = 0; j < 4; ++j) {
    const int n = n0 + 16 * j + c;
    const float bv = b1[n];
#pragma unroll
    for (int rg = 0; rg < 2; ++rg)
#pragma unroll
      for (int r = 0; r < 4; ++r) {
        float v = acc[rg][j][r] + bv;
        A[16 * rg + 4 * g + r][n] = bfu(v > 0.f ? v : 0.f);
      }
  }
  __syncthreads();

  // ---- GEMM3: h @ W2 ----
#pragma unroll
  for (int rg = 0; rg < 2; ++rg)
#pragma unroll
    for (int j = 0; j < 4; ++j) acc[rg][j] = zf4;
#pragma unroll
  for (int kk = 0; kk < 256; kk += 32) {
    bf16x8 af0 = *(const bf16x8*)&A[c][kk + 8 * g];
    bf16x8 af1 = *(const bf16x8*)&A[16 + c][kk + 8 * g];
#pragma unroll
    for (int j = 0; j < 4; ++j) {
      bf16x8 bfr = asfrag(*(const uint4*)(w2T + (size_t)(n0 + 16 * j + c) * 256 + kk + 8 * g));
      acc[0][j] = __builtin_amdgcn_mfma_f32_16x16x32_bf16(af0, bfr, acc[0][j], 0, 0, 0);
      acc[1][j] = __builtin_amdgcn_mfma_f32_16x16x32_bf16(af1, bfr, acc[1][j], 0, 0, 0);
    }
  }
  // ---- epilogue3: z = acc + b2 + t1 (regs); LN2 -> out ----
  {
    float b2v[4];
#pragma unroll
    for (int j = 0; j < 4; ++j) b2v[j] = b2[n0 + 16 * j + c];
#pragma unroll
    for (int rg = 0; rg < 2; ++rg)
#pragma unroll
      for (int r = 0; r < 4; ++r) {
        const int rl = 16 * rg + 4 * g + r;
        float a1 = 0.f, a2 = 0.f;
#pragma unroll
        for (int j = 0; j < 4; ++j) {
          float z = acc[rg][j][r] + b2v[j] + t1[rg][j][r];
          t1[rg][j][r] = z;
          a1 += z; a2 += z * z;
        }
#pragma unroll
        for (int off = 1; off < 16; off <<= 1) {
          a1 += __shfl_xor(a1, off);
          a2 += __shfl_xor(a2, off);
        }
        if (c == 0) { PS1[rl][w] = a1; PS2[rl][w] = a2; }
      }
  }
  __syncthreads();
#pragma unroll
  for (int rg = 0; rg < 2; ++rg)
#pragma unroll
    for (int r = 0; r < 4; ++r) {
      const int rl = 16 * rg + 4 * g + r;
      float s1 = PS1[rl][0] + PS1[rl][1] + PS1[rl][2] + PS1[rl][3];
      float s2 = PS2[rl][0] + PS2[rl][1] + PS2[rl][2] + PS2[rl][3];
      mean[rg][r] = s1 * (1.f / 256.f);
      inv[rg][r] = rsqrtf(s2 * (1.f / 256.f) - mean[rg][r] * mean[rg][r] + 1e-5f);
    }
#pragma unroll
  for (int j = 0; j < 4; ++j) {
    const int n = n0 + 16 * j + c;
    const float gv = g2[n], bev = be2[n];
#pragma unroll
    for (int rg = 0; rg < 2; ++rg)
#pragma unroll
      for (int r = 0; r < 4; ++r)
        out[(size_t)(m0 + 16 * rg + 4 * g + r) * 256 + n]
            = (t1[rg][j][r] - mean[rg][r]) * inv[rg][r] * gv + bev;
  }
}

extern "C" void kernel_launch(void* const* d_in, const int* in_sizes, int n_in,
                              void* d_out, int out_size, void* d_ws, size_t ws_size,
                              hipStream_t stream) {
  const float* qdt   = (const float*)d_in[0];
  const float* boxes = (const float*)d_in[1];
  const int*   mask  = (const int*)d_in[2];
  const float* Wq = (const float*)d_in[3];
  const float* bq = (const float*)d_in[4];
  const float* Wk = (const float*)d_in[5];
  const float* bk = (const float*)d_in[6];
  const float* Wv = (const float*)d_in[7];
  const float* bv = (const float*)d_in[8];
  const float* Wo = (const float*)d_in[9];
  const float* bo = (const float*)d_in[10];
  const float* W1 = (const float*)d_in[11];
  const float* b1 = (const float*)d_in[12];
  const float* W2 = (const float*)d_in[13];
  const float* b2 = (const float*)d_in[14];
  const float* g1  = (const float*)d_in[15];
  const float* be1 = (const float*)d_in[16];
  const float* g2  = (const float*)d_in[17];
  const float* be2 = (const float*)d_in[18];

  char* ws = (char*)d_ws;
  float* xp    = (float*)(ws + 0);          // [8192,256] f32 permuted residual
  u16*   xb    = (u16*)  (ws + 8388608);
  u16*   qbuf  = (u16*)  (ws + 12582912);   // q, LAMBDA-scaled
  u16*   kbuf  = (u16*)  (ws + 16777216);   // [B][H][2048][32]
  u16*   vtbuf = (u16*)  (ws + 20971520);   // [256][8192]
  u16*   obuf  = (u16*)  (ws + 25165824);
  u16*   wqkvT = (u16*)  (ws + 46137344);   // [768,256]
  u16*   woT   = (u16*)  (ws + 46530560);
  u16*   w1T   = (u16*)  (ws + 46661632);
  u16*   w2T   = (u16*)  (ws + 46792704);
  float* bqkv  = (float*)(ws + 46923776);
  u32*   m1    = (u32*)  (ws + 46926848);   // [2048][64] u32 mask bits (512 KB)

  // merged prep: xp/xb (2048) + mask-bits (512) + weight-tiles (96) + bias (1)
  prep_kernel<<<2657, 256, 0, stream>>>(qdt, boxes, mask, Wq, Wk, Wv, Wo, W1, W2,
                                        bq, bk, bv, xp, xb, m1,
                                        wqkvT, woT, w1T, w2T, bqkv);
  // fused Q(scaled)/K(relayout) + V^T: 1024 + 512 blocks
  gemm_qkvt_kernel<<<1536, 256, 0, stream>>>(xb, wqkvT, bqkv, qbuf, kbuf, vtbuf);
  // attention: 1024 blocks x (b,h,64q), XCD-swizzled
  attn_kernel<<<1024, 256, 0, stream>>>(qbuf, kbuf, vtbuf, m1, obuf);
  // fused tail: Wo+res -> LN1 -> FF1+relu -> FF2+res -> LN2 -> d_out
  tail_kernel<<<256, 256, 0, stream>>>(obuf, woT, w1T, w2T, xp,
                                       bo, b1, b2, g1, be1, g2, be2, (float*)d_out);
}